// Round 2
// baseline (184.573 us; speedup 1.0000x reference)
//
#include <hip/hip_runtime.h>
#include <hip/hip_bf16.h>
#include <cstdint>
#include <cstddef>

#define B_DIM 32
#define S_DIM 1024
#define H_DIM 1024
#define M_DIM (B_DIM * S_DIM)   // 32768

typedef __attribute__((ext_vector_type(8))) short bf16x8;
typedef __attribute__((ext_vector_type(4))) float f32x4;
typedef __attribute__((ext_vector_type(4))) int int4v;

// round-to-nearest-even fp32 -> bf16 (bit trick; no NaN inputs here)
static __device__ __forceinline__ unsigned short f2bf(float f) {
  unsigned u = __float_as_uint(f);
  u = (u + 0x7FFFu + ((u >> 16) & 1u)) >> 16;
  return (unsigned short)u;
}

// ---------------- K0: W_w fp32 -> bf16 ----------------
__global__ void k_convert_w(const float* __restrict__ W, unsigned short* __restrict__ Wb) {
  int idx = blockIdx.x * 256 + threadIdx.x;        // 0 .. 262143 (1M/4)
  float4 v = ((const float4*)W)[idx];
  ushort4 o;
  o.x = f2bf(v.x); o.y = f2bf(v.y); o.z = f2bf(v.z); o.w = f2bf(v.w);
  ((ushort4*)Wb)[idx] = o;
}

// ---------------- K1: U_h[b,o] = sum_h dh[b,h]*U_w[o,h] (fp32) ----------------
__global__ void k_uh(const float* __restrict__ dh, const float* __restrict__ Uw,
                     float* __restrict__ Uh) {
  const int wave = threadIdx.x >> 6;
  const int lane = threadIdx.x & 63;
  const int o = blockIdx.x * 4 + wave;             // 0..1023
  float uw[16];
#pragma unroll
  for (int k = 0; k < 16; ++k) uw[k] = Uw[o * H_DIM + k * 64 + lane];
  for (int b = 0; b < B_DIM; ++b) {
    float acc = 0.f;
#pragma unroll
    for (int k = 0; k < 16; ++k) acc += uw[k] * dh[b * H_DIM + k * 64 + lane];
#pragma unroll
    for (int msk = 32; msk >= 1; msk >>= 1) acc += __shfl_xor(acc, msk, 64);
    if (lane == 0) Uh[b * H_DIM + o] = acc;
  }
}

// ---------------- K2: fused  att_p[nt][m] = sum_{o in tile} tanh(enc@Ww^T + Uh)*v ----------------
#define BM 128
#define BN 128
#define BK 64
#define KSTEPS (H_DIM / BK)   // 16

__launch_bounds__(256)
__global__ void k_att(const float* __restrict__ enc,
                      const unsigned short* __restrict__ Wb,
                      const float* __restrict__ Uh,
                      const float* __restrict__ vw,
                      float* __restrict__ att_p) {
  __shared__ __align__(16) char lds[32 * 1024];
  char* As = lds;            // [128][64] bf16, XOR-swizzled, 16 KB
  char* Bs = lds + 16384;    // [128][64] bf16 (rows = o), XOR-swizzled, 16 KB

  // XCD-friendly tile mapping: 8 consecutive blocks on one XCD share an M-panel
  const int bid = blockIdx.x;            // 0..2047
  const int xj = bid & 7;
  const int q  = bid >> 3;               // 0..255
  const int n_tile = q & 7;
  const int m_tile = ((q >> 3) << 3) | xj;   // 0..255, bijective
  const int m0 = m_tile * BM;
  const int n0 = n_tile * BN;
  const int b  = m0 >> 10;               // batch (BM divides S)

  const int tid  = threadIdx.x;
  const int wid  = tid >> 6;
  const int lane = tid & 63;
  const int wm = (wid >> 1) * 64;        // wave tile origin (2x2 waves, 64x64 each)
  const int wn = (wid & 1) * 64;

  const int fr_row = lane & 15;
  const int fr_k8  = lane >> 4;          // 0..3

  f32x4 acc[4][4];
#pragma unroll
  for (int mf = 0; mf < 4; ++mf)
#pragma unroll
    for (int nf = 0; nf < 4; ++nf) acc[mf][nf] = (f32x4)(0.0f);

  for (int ks = 0; ks < KSTEPS; ++ks) {
    const int k0 = ks * BK;
    __syncthreads();   // previous compute done before overwriting LDS
#pragma unroll
    for (int i = 0; i < 4; ++i) {
      const int chunk = i * 256 + tid;       // 0..1023
      const int r  = chunk >> 3;             // 0..127
      const int c8 = chunk & 7;              // 8-elem k-chunk
      const int addr = (r * 128 + c8 * 16) ^ ((r & 7) << 4);
      // A: convert fp32 -> bf16
      const float4* gp = (const float4*)&enc[(size_t)(m0 + r) * H_DIM + k0 + c8 * 8];
      float4 lo = gp[0], hi = gp[1];
      bf16x8 w;
      w[0] = (short)f2bf(lo.x); w[1] = (short)f2bf(lo.y);
      w[2] = (short)f2bf(lo.z); w[3] = (short)f2bf(lo.w);
      w[4] = (short)f2bf(hi.x); w[5] = (short)f2bf(hi.y);
      w[6] = (short)f2bf(hi.z); w[7] = (short)f2bf(hi.w);
      *(bf16x8*)(As + addr) = w;
      // B: already bf16, raw 16B copy
      const int4v gb = *(const int4v*)&Wb[(size_t)(n0 + r) * H_DIM + k0 + c8 * 8];
      *(int4v*)(Bs + addr) = gb;
    }
    __syncthreads();
#pragma unroll
    for (int kh = 0; kh < 2; ++kh) {
      const int kb = kh * 32 + fr_k8 * 8;    // lane's k-offset within BK
      bf16x8 af[4], bfr[4];
#pragma unroll
      for (int mf = 0; mf < 4; ++mf) {
        const int row = wm + mf * 16 + fr_row;
        const int addr = (row * 128 + kb * 2) ^ ((row & 7) << 4);
        af[mf] = *(const bf16x8*)(As + addr);
      }
#pragma unroll
      for (int nf = 0; nf < 4; ++nf) {
        const int row = wn + nf * 16 + fr_row;
        const int addr = (row * 128 + kb * 2) ^ ((row & 7) << 4);
        bfr[nf] = *(const bf16x8*)(Bs + addr);
      }
#pragma unroll
      for (int mf = 0; mf < 4; ++mf)
#pragma unroll
        for (int nf = 0; nf < 4; ++nf)
          acc[mf][nf] = __builtin_amdgcn_mfma_f32_16x16x32_bf16(af[mf], bfr[nf], acc[mf][nf], 0, 0, 0);
    }
  }

  // All LDS reads of As/Bs are done before we reuse LDS for the cross-wave reduce.
  __syncthreads();
  float* red = (float*)lds;   // [4 waves][64 rows] partial sums over each wave's 64 o's

  // Epilogue: val = tanh(acc + Uh[b,o]) * v[o]; row-reduce over this wave's 64 o's.
  // D frag layout: col = lane&15 (n), row = (lane>>4)*4 + reg (m)   [m89-verified]
  const int col = lane & 15;
  const int rhi = lane >> 4;
  float uh[4], vv[4];
#pragma unroll
  for (int nf = 0; nf < 4; ++nf) {
    const int o = n0 + wn + nf * 16 + col;
    uh[nf] = Uh[b * H_DIM + o];
    vv[nf] = vw[o];
  }
#pragma unroll
  for (int mf = 0; mf < 4; ++mf) {
    float rs[4];
#pragma unroll
    for (int jj = 0; jj < 4; ++jj) {
      float s = 0.f;
#pragma unroll
      for (int nf = 0; nf < 4; ++nf) {
        const float x = acc[mf][nf][jj] + uh[nf];
        s += tanhf(x) * vv[nf];
      }
      rs[jj] = s;
    }
    // reduce across the 16 cols held by this 16-lane group
#pragma unroll
    for (int msk = 1; msk < 16; msk <<= 1) {
#pragma unroll
      for (int jj = 0; jj < 4; ++jj) rs[jj] += __shfl_xor(rs[jj], msk, 64);
    }
    if (col == 0) {
#pragma unroll
      for (int jj = 0; jj < 4; ++jj) {
        const int local = mf * 16 + rhi * 4 + jj;      // row within wave's 64
        red[wid * 64 + local] = rs[jj];
      }
    }
  }
  __syncthreads();

  // Combine the two o-half waves per row group and store 128 rows.
  if (tid < 128) {
    const int half = tid >> 6;     // row group: waves {0,1} own rows 0..63, {2,3} own 64..127
    const int loc  = tid & 63;
    const float sum = red[(half * 2) * 64 + loc] + red[(half * 2 + 1) * 64 + loc];
    att_p[(size_t)n_tile * M_DIM + m0 + tid] = sum;
  }
}

// ---------------- K3: softmax over s, per b; writes alpha into d_out ----------------
__global__ void k_softmax(const float* __restrict__ att_p, float* __restrict__ alpha) {
  const int b = blockIdx.x;
  const int tid = threadIdx.x;
  __shared__ float red[8];
  float a[4];
  float mx = -1e30f;
#pragma unroll
  for (int i = 0; i < 4; ++i) {
    const int s = i * 256 + tid;
    float v = 0.f;
#pragma unroll
    for (int t = 0; t < 8; ++t) v += att_p[(size_t)t * M_DIM + b * S_DIM + s];
    a[i] = v;
    mx = fmaxf(mx, v);
  }
#pragma unroll
  for (int msk = 32; msk >= 1; msk >>= 1) mx = fmaxf(mx, __shfl_xor(mx, msk, 64));
  if ((tid & 63) == 0) red[tid >> 6] = mx;
  __syncthreads();
  mx = fmaxf(fmaxf(red[0], red[1]), fmaxf(red[2], red[3]));
  float sum = 0.f;
#pragma unroll
  for (int i = 0; i < 4; ++i) { a[i] = __expf(a[i] - mx); sum += a[i]; }
#pragma unroll
  for (int msk = 32; msk >= 1; msk >>= 1) sum += __shfl_xor(sum, msk, 64);
  if ((tid & 63) == 0) red[4 + (tid >> 6)] = sum;
  __syncthreads();
  const float inv = 1.f / (red[4] + red[5] + red[6] + red[7]);
#pragma unroll
  for (int i = 0; i < 4; ++i) alpha[b * S_DIM + i * 256 + tid] = a[i] * inv;
}

// ---------------- K4: context partials over s-quarters ----------------
__global__ void k_ctx(const float* __restrict__ enc, const float* __restrict__ alpha,
                      float* __restrict__ ctx_p) {
  const int bid = blockIdx.x;           // 512 = b(32) * hc(4) * sq(4)
  const int b  = bid >> 4;
  const int hc = (bid >> 2) & 3;
  const int sq = bid & 3;
  const int h = hc * 256 + threadIdx.x;
  const float* ap = &alpha[b * S_DIM + sq * 256];
  const float* ep = &enc[(size_t)b * S_DIM * H_DIM + (size_t)(sq * 256) * H_DIM + h];
  float acc = 0.f;
  for (int s = 0; s < 256; ++s) acc += ap[s] * ep[(size_t)s * H_DIM];
  ctx_p[(size_t)sq * (B_DIM * H_DIM) + b * H_DIM + h] = acc;
}

// ---------------- K5: reduce context partials -> d_out ----------------
__global__ void k_ctx_reduce(const float* __restrict__ ctx_p, float* __restrict__ ctx) {
  const int i = blockIdx.x * 256 + threadIdx.x;  // 0..32767
  ctx[i] = ctx_p[i] + ctx_p[32768 + i] + ctx_p[65536 + i] + ctx_p[98304 + i];
}

extern "C" void kernel_launch(void* const* d_in, const int* in_sizes, int n_in,
                              void* d_out, int out_size, void* d_ws, size_t ws_size,
                              hipStream_t stream) {
  (void)in_sizes; (void)n_in; (void)out_size; (void)ws_size;
  const float* dh  = (const float*)d_in[0];
  const float* enc = (const float*)d_in[1];
  const float* Uw  = (const float*)d_in[2];
  const float* Ww  = (const float*)d_in[3];
  const float* vw  = (const float*)d_in[4];
  float* ctx_out = (float*)d_out;                 // [32,1024]
  float* alpha   = (float*)d_out + M_DIM;         // [32,1024]

  char* ws = (char*)d_ws;
  unsigned short* Wb = (unsigned short*)ws;                         // 2 MB bf16 W_w
  float* Uh    = (float*)(ws + (2u << 20));                         // 128 KB
  float* att_p = (float*)(ws + (2u << 20) + (128u << 10));          // 8*32768*4 = 1 MB
  float* ctx_p = (float*)(ws + (2u << 20) + (128u << 10) + (1u << 20)); // 512 KB

  k_convert_w<<<1024, 256, 0, stream>>>(Ww, Wb);
  k_uh<<<256, 256, 0, stream>>>(dh, Uw, Uh);
  k_att<<<2048, 256, 0, stream>>>(enc, Wb, Uh, vw, att_p);
  k_softmax<<<32, 256, 0, stream>>>(att_p, alpha);
  k_ctx<<<512, 256, 0, stream>>>(enc, alpha, ctx_p);
  k_ctx_reduce<<<128, 256, 0, stream>>>(ctx_p, ctx_out);
}

// Round 3
// 181.027 us; speedup vs baseline: 1.0196x; 1.0196x over previous
//
#include <hip/hip_runtime.h>
#include <hip/hip_bf16.h>
#include <cstdint>
#include <cstddef>

#define B_DIM 32
#define S_DIM 1024
#define H_DIM 1024
#define M_DIM (B_DIM * S_DIM)   // 32768

typedef __attribute__((ext_vector_type(8))) short bf16x8;
typedef __attribute__((ext_vector_type(4))) float f32x4;
typedef __attribute__((ext_vector_type(4))) int int4v;

// round-to-nearest-even fp32 -> bf16 (bit trick; no NaN inputs here)
static __device__ __forceinline__ unsigned short f2bf(float f) {
  unsigned u = __float_as_uint(f);
  u = (u + 0x7FFFu + ((u >> 16) & 1u)) >> 16;
  return (unsigned short)u;
}
static __device__ __forceinline__ float bf2f(unsigned short u) {
  return __uint_as_float(((unsigned)u) << 16);
}

// async global(16B/lane) -> LDS, wave-uniform LDS base, per-lane global addr
static __device__ __forceinline__ void gload16(const unsigned short* g, char* l) {
  __builtin_amdgcn_global_load_lds(
      (const __attribute__((address_space(1))) unsigned int*)g,
      (__attribute__((address_space(3))) unsigned int*)l, 16, 0, 0);
}

// ---------------- K0a: W_w fp32 -> bf16 ----------------
__global__ void k_convert_w(const float* __restrict__ W, unsigned short* __restrict__ Wb) {
  int idx = blockIdx.x * 256 + threadIdx.x;        // 0 .. 262143 (1M/4)
  float4 v = ((const float4*)W)[idx];
  ushort4 o;
  o.x = f2bf(v.x); o.y = f2bf(v.y); o.z = f2bf(v.z); o.w = f2bf(v.w);
  ((ushort4*)Wb)[idx] = o;
}

// ---------------- K0b: enc fp32 -> bf16 (grid-stride, 8 elems/thread/iter) ----------------
__global__ void k_convert_enc(const float* __restrict__ E, unsigned short* __restrict__ Eb) {
  const int n8 = M_DIM * (H_DIM / 8);              // 4,194,304 chunks
  const int stride = gridDim.x * 256;
  for (int idx = blockIdx.x * 256 + threadIdx.x; idx < n8; idx += stride) {
    const float4* gp = (const float4*)(E + (size_t)idx * 8);
    float4 lo = gp[0], hi = gp[1];
    bf16x8 w;
    w[0] = (short)f2bf(lo.x); w[1] = (short)f2bf(lo.y);
    w[2] = (short)f2bf(lo.z); w[3] = (short)f2bf(lo.w);
    w[4] = (short)f2bf(hi.x); w[5] = (short)f2bf(hi.y);
    w[6] = (short)f2bf(hi.z); w[7] = (short)f2bf(hi.w);
    *(bf16x8*)(Eb + (size_t)idx * 8) = w;
  }
}

// ---------------- K1: U_h[b,o] = sum_h dh[b,h]*U_w[o,h] (fp32) ----------------
__global__ void k_uh(const float* __restrict__ dh, const float* __restrict__ Uw,
                     float* __restrict__ Uh) {
  const int wave = threadIdx.x >> 6;
  const int lane = threadIdx.x & 63;
  const int o = blockIdx.x * 4 + wave;             // 0..1023
  float uw[16];
#pragma unroll
  for (int k = 0; k < 16; ++k) uw[k] = Uw[o * H_DIM + k * 64 + lane];
  for (int b = 0; b < B_DIM; ++b) {
    float acc = 0.f;
#pragma unroll
    for (int k = 0; k < 16; ++k) acc += uw[k] * dh[b * H_DIM + k * 64 + lane];
#pragma unroll
    for (int msk = 32; msk >= 1; msk >>= 1) acc += __shfl_xor(acc, msk, 64);
    if (lane == 0) Uh[b * H_DIM + o] = acc;
  }
}

// ---------------- K2 (fast): fused att via global_load_lds bf16 GEMM ----------------
#define BM 128
#define BN 128
#define BK 64
#define KSTEPS (H_DIM / BK)   // 16

__launch_bounds__(256)
__global__ void k_att2(const unsigned short* __restrict__ Eb,
                       const unsigned short* __restrict__ Wb,
                       const float* __restrict__ Uh,
                       const float* __restrict__ vw,
                       float* __restrict__ att_p) {
  __shared__ __align__(16) char lds[32 * 1024];
  char* As = lds;            // [128][64] bf16, XOR-swizzled content, 16 KB
  char* Bs = lds + 16384;    // [128][64] bf16 (rows = o), 16 KB

  // XCD-friendly: 8 consecutive blocks (one XCD) share an M-panel
  const int bid = blockIdx.x;            // 0..2047
  const int xj = bid & 7;
  const int q  = bid >> 3;
  const int n_tile = q & 7;
  const int m_tile = ((q >> 3) << 3) | xj;
  const int m0 = m_tile * BM;
  const int n0 = n_tile * BN;
  const int b  = m0 >> 10;

  const int tid  = threadIdx.x;
  const int wid  = tid >> 6;
  const int lane = tid & 63;
  const int wm = (wid >> 1) * 64;
  const int wn = (wid & 1) * 64;

  // Staging map: LDS is written linearly (chunk = i*256+tid, 16B each).
  // Desired content: LDS[(r*128 + c*16) ^ ((r&7)<<4)] = global(r,c).
  // => for linear offset x: r = x>>7, c = ((x>>4)&7) ^ (r&7)  (inverse-swizzled source).
  size_t offA[4], offB[4];
  int ldsoff[4];
#pragma unroll
  for (int i = 0; i < 4; ++i) {
    const int chunk = i * 256 + tid;
    const int r  = chunk >> 3;
    const int c8 = (chunk & 7) ^ (r & 7);
    offA[i] = (size_t)(m0 + r) * H_DIM + c8 * 8;
    offB[i] = (size_t)(n0 + r) * H_DIM + c8 * 8;
    ldsoff[i] = i * 4096 + wid * 1024;       // wave-uniform base; HW adds lane*16
  }

  const int fr_row = lane & 15;
  const int fr_k8  = lane >> 4;

  f32x4 acc[4][4];
#pragma unroll
  for (int mf = 0; mf < 4; ++mf)
#pragma unroll
    for (int nf = 0; nf < 4; ++nf) acc[mf][nf] = (f32x4)(0.0f);

  for (int ks = 0; ks < KSTEPS; ++ks) {
    const int k0 = ks * BK;
    __syncthreads();                      // previous tile's ds_reads done
#pragma unroll
    for (int i = 0; i < 4; ++i) {
      gload16(Eb + offA[i] + k0, As + ldsoff[i]);
      gload16(Wb + offB[i] + k0, Bs + ldsoff[i]);
    }
    __syncthreads();                      // drains vmcnt(0), data ready
#pragma unroll
    for (int kh = 0; kh < 2; ++kh) {
      const int kb = kh * 32 + fr_k8 * 8;
      bf16x8 af[4], bfr[4];
#pragma unroll
      for (int mf = 0; mf < 4; ++mf) {
        const int row = wm + mf * 16 + fr_row;
        const int addr = (row * 128 + kb * 2) ^ ((row & 7) << 4);
        af[mf] = *(const bf16x8*)(As + addr);
      }
#pragma unroll
      for (int nf = 0; nf < 4; ++nf) {
        const int row = wn + nf * 16 + fr_row;
        const int addr = (row * 128 + kb * 2) ^ ((row & 7) << 4);
        bfr[nf] = *(const bf16x8*)(Bs + addr);
      }
#pragma unroll
      for (int mf = 0; mf < 4; ++mf)
#pragma unroll
        for (int nf = 0; nf < 4; ++nf)
          acc[mf][nf] = __builtin_amdgcn_mfma_f32_16x16x32_bf16(af[mf], bfr[nf], acc[mf][nf], 0, 0, 0);
    }
  }

  __syncthreads();
  float* red = (float*)lds;   // [4 waves][64 rows]

  // Epilogue: tanh(acc + Uh)*v, reduce over this wave's 64 o's.
  // D frag: col = lane&15 (n), row = (lane>>4)*4 + reg (m)
  const int col = lane & 15;
  const int rhi = lane >> 4;
  float uh[4], vv[4];
#pragma unroll
  for (int nf = 0; nf < 4; ++nf) {
    const int o = n0 + wn + nf * 16 + col;
    uh[nf] = Uh[b * H_DIM + o];
    vv[nf] = vw[o];
  }
#pragma unroll
  for (int mf = 0; mf < 4; ++mf) {
    float rs[4];
#pragma unroll
    for (int jj = 0; jj < 4; ++jj) {
      float s = 0.f;
#pragma unroll
      for (int nf = 0; nf < 4; ++nf) {
        const float x = acc[mf][nf][jj] + uh[nf];
        s += tanhf(x) * vv[nf];
      }
      rs[jj] = s;
    }
#pragma unroll
    for (int msk = 1; msk < 16; msk <<= 1) {
#pragma unroll
      for (int jj = 0; jj < 4; ++jj) rs[jj] += __shfl_xor(rs[jj], msk, 64);
    }
    if (col == 0) {
#pragma unroll
      for (int jj = 0; jj < 4; ++jj) {
        const int local = mf * 16 + rhi * 4 + jj;
        red[wid * 64 + local] = rs[jj];
      }
    }
  }
  __syncthreads();
  if (tid < 128) {
    const int half = tid >> 6;
    const int loc  = tid & 63;
    const float sum = red[(half * 2) * 64 + loc] + red[(half * 2 + 1) * 64 + loc];
    att_p[(size_t)n_tile * M_DIM + m0 + tid] = sum;
  }
}

// ---------------- K2 (fallback): round-2 reg-staged fp32-input version ----------------
__launch_bounds__(256)
__global__ void k_att(const float* __restrict__ enc,
                      const unsigned short* __restrict__ Wb,
                      const float* __restrict__ Uh,
                      const float* __restrict__ vw,
                      float* __restrict__ att_p) {
  __shared__ __align__(16) char lds[32 * 1024];
  char* As = lds;
  char* Bs = lds + 16384;
  const int bid = blockIdx.x;
  const int xj = bid & 7;
  const int q  = bid >> 3;
  const int n_tile = q & 7;
  const int m_tile = ((q >> 3) << 3) | xj;
  const int m0 = m_tile * BM;
  const int n0 = n_tile * BN;
  const int b  = m0 >> 10;
  const int tid  = threadIdx.x;
  const int wid  = tid >> 6;
  const int lane = tid & 63;
  const int wm = (wid >> 1) * 64;
  const int wn = (wid & 1) * 64;
  const int fr_row = lane & 15;
  const int fr_k8  = lane >> 4;
  f32x4 acc[4][4];
#pragma unroll
  for (int mf = 0; mf < 4; ++mf)
#pragma unroll
    for (int nf = 0; nf < 4; ++nf) acc[mf][nf] = (f32x4)(0.0f);
  for (int ks = 0; ks < KSTEPS; ++ks) {
    const int k0 = ks * BK;
    __syncthreads();
#pragma unroll
    for (int i = 0; i < 4; ++i) {
      const int chunk = i * 256 + tid;
      const int r  = chunk >> 3;
      const int c8 = chunk & 7;
      const int addr = (r * 128 + c8 * 16) ^ ((r & 7) << 4);
      const float4* gp = (const float4*)&enc[(size_t)(m0 + r) * H_DIM + k0 + c8 * 8];
      float4 lo = gp[0], hi = gp[1];
      bf16x8 w;
      w[0] = (short)f2bf(lo.x); w[1] = (short)f2bf(lo.y);
      w[2] = (short)f2bf(lo.z); w[3] = (short)f2bf(lo.w);
      w[4] = (short)f2bf(hi.x); w[5] = (short)f2bf(hi.y);
      w[6] = (short)f2bf(hi.z); w[7] = (short)f2bf(hi.w);
      *(bf16x8*)(As + addr) = w;
      const int4v gb = *(const int4v*)&Wb[(size_t)(n0 + r) * H_DIM + k0 + c8 * 8];
      *(int4v*)(Bs + addr) = gb;
    }
    __syncthreads();
#pragma unroll
    for (int kh = 0; kh < 2; ++kh) {
      const int kb = kh * 32 + fr_k8 * 8;
      bf16x8 af[4], bfr[4];
#pragma unroll
      for (int mf = 0; mf < 4; ++mf) {
        const int row = wm + mf * 16 + fr_row;
        const int addr = (row * 128 + kb * 2) ^ ((row & 7) << 4);
        af[mf] = *(const bf16x8*)(As + addr);
      }
#pragma unroll
      for (int nf = 0; nf < 4; ++nf) {
        const int row = wn + nf * 16 + fr_row;
        const int addr = (row * 128 + kb * 2) ^ ((row & 7) << 4);
        bfr[nf] = *(const bf16x8*)(Bs + addr);
      }
#pragma unroll
      for (int mf = 0; mf < 4; ++mf)
#pragma unroll
        for (int nf = 0; nf < 4; ++nf)
          acc[mf][nf] = __builtin_amdgcn_mfma_f32_16x16x32_bf16(af[mf], bfr[nf], acc[mf][nf], 0, 0, 0);
    }
  }
  __syncthreads();
  float* red = (float*)lds;
  const int col = lane & 15;
  const int rhi = lane >> 4;
  float uh[4], vv[4];
#pragma unroll
  for (int nf = 0; nf < 4; ++nf) {
    const int o = n0 + wn + nf * 16 + col;
    uh[nf] = Uh[b * H_DIM + o];
    vv[nf] = vw[o];
  }
#pragma unroll
  for (int mf = 0; mf < 4; ++mf) {
    float rs[4];
#pragma unroll
    for (int jj = 0; jj < 4; ++jj) {
      float s = 0.f;
#pragma unroll
      for (int nf = 0; nf < 4; ++nf) {
        const float x = acc[mf][nf][jj] + uh[nf];
        s += tanhf(x) * vv[nf];
      }
      rs[jj] = s;
    }
#pragma unroll
    for (int msk = 1; msk < 16; msk <<= 1) {
#pragma unroll
      for (int jj = 0; jj < 4; ++jj) rs[jj] += __shfl_xor(rs[jj], msk, 64);
    }
    if (col == 0) {
#pragma unroll
      for (int jj = 0; jj < 4; ++jj) {
        const int local = mf * 16 + rhi * 4 + jj;
        red[wid * 64 + local] = rs[jj];
      }
    }
  }
  __syncthreads();
  if (tid < 128) {
    const int half = tid >> 6;
    const int loc  = tid & 63;
    const float sum = red[(half * 2) * 64 + loc] + red[(half * 2 + 1) * 64 + loc];
    att_p[(size_t)n_tile * M_DIM + m0 + tid] = sum;
  }
}

// ---------------- K3: softmax over s, per b; writes alpha ----------------
__global__ void k_softmax(const float* __restrict__ att_p, float* __restrict__ alpha) {
  const int b = blockIdx.x;
  const int tid = threadIdx.x;
  __shared__ float red[8];
  float a[4];
  float mx = -1e30f;
#pragma unroll
  for (int i = 0; i < 4; ++i) {
    const int s = i * 256 + tid;
    float v = 0.f;
#pragma unroll
    for (int t = 0; t < 8; ++t) v += att_p[(size_t)t * M_DIM + b * S_DIM + s];
    a[i] = v;
    mx = fmaxf(mx, v);
  }
#pragma unroll
  for (int msk = 32; msk >= 1; msk >>= 1) mx = fmaxf(mx, __shfl_xor(mx, msk, 64));
  if ((tid & 63) == 0) red[tid >> 6] = mx;
  __syncthreads();
  mx = fmaxf(fmaxf(red[0], red[1]), fmaxf(red[2], red[3]));
  float sum = 0.f;
#pragma unroll
  for (int i = 0; i < 4; ++i) { a[i] = __expf(a[i] - mx); sum += a[i]; }
#pragma unroll
  for (int msk = 32; msk >= 1; msk >>= 1) sum += __shfl_xor(sum, msk, 64);
  if ((tid & 63) == 0) red[4 + (tid >> 6)] = sum;
  __syncthreads();
  const float inv = 1.f / (red[4] + red[5] + red[6] + red[7]);
#pragma unroll
  for (int i = 0; i < 4; ++i) alpha[b * S_DIM + i * 256 + tid] = a[i] * inv;
}

// ---------------- K4: context partials (bf16 enc) ----------------
__global__ void k_ctx_bf(const unsigned short* __restrict__ Eb, const float* __restrict__ alpha,
                         float* __restrict__ ctx_p) {
  const int bid = blockIdx.x;           // 512 = b(32) * hc(4) * sq(4)
  const int b  = bid >> 4;
  const int hc = (bid >> 2) & 3;
  const int sq = bid & 3;
  const int h = hc * 256 + threadIdx.x;
  const float* ap = &alpha[b * S_DIM + sq * 256];
  const unsigned short* ep = Eb + (size_t)b * S_DIM * H_DIM + (size_t)(sq * 256) * H_DIM + h;
  float acc = 0.f;
#pragma unroll 8
  for (int s = 0; s < 256; ++s) acc += ap[s] * bf2f(ep[(size_t)s * H_DIM]);
  ctx_p[(size_t)sq * (B_DIM * H_DIM) + b * H_DIM + h] = acc;
}

// ---------------- K4 (fallback): fp32 enc ----------------
__global__ void k_ctx(const float* __restrict__ enc, const float* __restrict__ alpha,
                      float* __restrict__ ctx_p) {
  const int bid = blockIdx.x;
  const int b  = bid >> 4;
  const int hc = (bid >> 2) & 3;
  const int sq = bid & 3;
  const int h = hc * 256 + threadIdx.x;
  const float* ap = &alpha[b * S_DIM + sq * 256];
  const float* ep = &enc[(size_t)b * S_DIM * H_DIM + (size_t)(sq * 256) * H_DIM + h];
  float acc = 0.f;
#pragma unroll 8
  for (int s = 0; s < 256; ++s) acc += ap[s] * ep[(size_t)s * H_DIM];
  ctx_p[(size_t)sq * (B_DIM * H_DIM) + b * H_DIM + h] = acc;
}

// ---------------- K5: reduce context partials -> d_out ----------------
__global__ void k_ctx_reduce(const float* __restrict__ ctx_p, float* __restrict__ ctx) {
  const int i = blockIdx.x * 256 + threadIdx.x;
  ctx[i] = ctx_p[i] + ctx_p[32768 + i] + ctx_p[65536 + i] + ctx_p[98304 + i];
}

extern "C" void kernel_launch(void* const* d_in, const int* in_sizes, int n_in,
                              void* d_out, int out_size, void* d_ws, size_t ws_size,
                              hipStream_t stream) {
  (void)in_sizes; (void)n_in; (void)out_size;
  const float* dh  = (const float*)d_in[0];
  const float* enc = (const float*)d_in[1];
  const float* Uw  = (const float*)d_in[2];
  const float* Ww  = (const float*)d_in[3];
  const float* vw  = (const float*)d_in[4];
  float* ctx_out = (float*)d_out;                 // [32,1024]
  float* alpha   = (float*)d_out + M_DIM;         // [32,1024]

  char* ws = (char*)d_ws;
  const size_t EB_BYTES = (size_t)M_DIM * H_DIM * 2;            // 64 MiB
  const size_t NEED = EB_BYTES + (2u << 20) + (128u << 10) + (1u << 20) + (512u << 10);

  if (ws_size >= NEED) {
    unsigned short* Eb = (unsigned short*)ws;
    unsigned short* Wb = (unsigned short*)(ws + EB_BYTES);
    float* Uh    = (float*)(ws + EB_BYTES + (2u << 20));
    float* att_p = (float*)(ws + EB_BYTES + (2u << 20) + (128u << 10));
    float* ctx_p = (float*)(ws + EB_BYTES + (2u << 20) + (128u << 10) + (1u << 20));

    k_convert_w<<<1024, 256, 0, stream>>>(Ww, Wb);
    k_convert_enc<<<2048, 256, 0, stream>>>(enc, Eb);
    k_uh<<<256, 256, 0, stream>>>(dh, Uw, Uh);
    k_att2<<<2048, 256, 0, stream>>>(Eb, Wb, Uh, vw, att_p);
    k_softmax<<<32, 256, 0, stream>>>(att_p, alpha);
    k_ctx_bf<<<512, 256, 0, stream>>>(Eb, alpha, ctx_p);
    k_ctx_reduce<<<128, 256, 0, stream>>>(ctx_p, ctx_out);
  } else {
    unsigned short* Wb = (unsigned short*)ws;
    float* Uh    = (float*)(ws + (2u << 20));
    float* att_p = (float*)(ws + (2u << 20) + (128u << 10));
    float* ctx_p = (float*)(ws + (2u << 20) + (128u << 10) + (1u << 20));

    k_convert_w<<<1024, 256, 0, stream>>>(Ww, Wb);
    k_uh<<<256, 256, 0, stream>>>(dh, Uw, Uh);
    k_att<<<2048, 256, 0, stream>>>(enc, Wb, Uh, vw, att_p);
    k_softmax<<<32, 256, 0, stream>>>(att_p, alpha);
    k_ctx<<<512, 256, 0, stream>>>(enc, alpha, ctx_p);
    k_ctx_reduce<<<128, 256, 0, stream>>>(ctx_p, ctx_out);
  }
}

// Round 4
// 170.111 us; speedup vs baseline: 1.0850x; 1.0642x over previous
//
#include <hip/hip_runtime.h>
#include <hip/hip_bf16.h>
#include <cstdint>
#include <cstddef>

#define B_DIM 32
#define S_DIM 1024
#define H_DIM 1024
#define M_DIM (B_DIM * S_DIM)   // 32768

typedef __attribute__((ext_vector_type(8))) short bf16x8;
typedef __attribute__((ext_vector_type(4))) float f32x4;
typedef __attribute__((ext_vector_type(4))) int int4v;

// round-to-nearest-even fp32 -> bf16 (bit trick; no NaN inputs here)
static __device__ __forceinline__ unsigned short f2bf(float f) {
  unsigned u = __float_as_uint(f);
  u = (u + 0x7FFFu + ((u >> 16) & 1u)) >> 16;
  return (unsigned short)u;
}
static __device__ __forceinline__ float bf2f(unsigned short u) {
  return __uint_as_float(((unsigned)u) << 16);
}
// exact identity tanh(x) = 1 - 2/(exp(2x)+1); __expf err ~2ulp, saturates correctly
static __device__ __forceinline__ float fast_tanh(float x) {
  return 1.f - 2.f / (__expf(2.f * x) + 1.f);
}

// async global(16B/lane) -> LDS, wave-uniform LDS base, per-lane global addr
static __device__ __forceinline__ void gload16(const unsigned short* g, char* l) {
  __builtin_amdgcn_global_load_lds(
      (const __attribute__((address_space(1))) unsigned int*)g,
      (__attribute__((address_space(3))) unsigned int*)l, 16, 0, 0);
}

// ---------------- K0a: W_w fp32 -> bf16 ----------------
__global__ void k_convert_w(const float* __restrict__ W, unsigned short* __restrict__ Wb) {
  int idx = blockIdx.x * 256 + threadIdx.x;        // 0 .. 262143 (1M/4)
  float4 v = ((const float4*)W)[idx];
  ushort4 o;
  o.x = f2bf(v.x); o.y = f2bf(v.y); o.z = f2bf(v.z); o.w = f2bf(v.w);
  ((ushort4*)Wb)[idx] = o;
}

// ---------------- K0b: enc fp32 -> bf16 ----------------
__global__ void k_convert_enc(const float* __restrict__ E, unsigned short* __restrict__ Eb) {
  const int n8 = M_DIM * (H_DIM / 8);              // 4,194,304 chunks
  const int stride = gridDim.x * 256;
  for (int idx = blockIdx.x * 256 + threadIdx.x; idx < n8; idx += stride) {
    const float4* gp = (const float4*)(E + (size_t)idx * 8);
    float4 lo = gp[0], hi = gp[1];
    bf16x8 w;
    w[0] = (short)f2bf(lo.x); w[1] = (short)f2bf(lo.y);
    w[2] = (short)f2bf(lo.z); w[3] = (short)f2bf(lo.w);
    w[4] = (short)f2bf(hi.x); w[5] = (short)f2bf(hi.y);
    w[6] = (short)f2bf(hi.z); w[7] = (short)f2bf(hi.w);
    *(bf16x8*)(Eb + (size_t)idx * 8) = w;
  }
}

// ---------------- K1: U_h[b,o] = sum_h dh[b,h]*U_w[o,h] (fp32) ----------------
__global__ void k_uh(const float* __restrict__ dh, const float* __restrict__ Uw,
                     float* __restrict__ Uh) {
  const int wave = threadIdx.x >> 6;
  const int lane = threadIdx.x & 63;
  const int o = blockIdx.x * 4 + wave;             // 0..1023
  float uw[16];
#pragma unroll
  for (int k = 0; k < 16; ++k) uw[k] = Uw[o * H_DIM + k * 64 + lane];
  for (int b = 0; b < B_DIM; ++b) {
    float acc = 0.f;
#pragma unroll
    for (int k = 0; k < 16; ++k) acc += uw[k] * dh[b * H_DIM + k * 64 + lane];
#pragma unroll
    for (int msk = 32; msk >= 1; msk >>= 1) acc += __shfl_xor(acc, msk, 64);
    if (lane == 0) Uh[b * H_DIM + o] = acc;
  }
}

// ---------------- K2 (fast): counted-vmcnt pipelined fused att GEMM ----------------
// BM=128, BN=256, BK=64. 512 threads = 8 waves (2M x 4N), per-wave 64x64 tile.
// LDS: 2 buffers x (A 16KB + B 32KB) = 96KB. 1 block/CU.
#define A3_BM 128
#define A3_BN 256
#define A3_BUF 49152
#define NT_FAST 4      // n_tiles

__launch_bounds__(512, 2)
__global__ void k_att3(const unsigned short* __restrict__ Eb,
                       const unsigned short* __restrict__ Wb,
                       const float* __restrict__ Uh,
                       const float* __restrict__ vw,
                       float* __restrict__ att_p) {
  __shared__ __align__(16) char lds[2 * A3_BUF];   // 96 KB

  // XCD-friendly: blocks with same (bid&7) sit on one XCD and share an M-panel
  const int bid = blockIdx.x;            // 0..1023
  const int xj = bid & 7;
  const int q  = bid >> 3;               // 0..127
  const int n_tile = q & 3;              // 0..3
  const int m_tile = ((q >> 2) << 3) | xj;   // 0..255, bijective
  const int m0 = m_tile * A3_BM;
  const int n0 = n_tile * A3_BN;
  const int b  = m0 >> 10;

  const int tid  = threadIdx.x;          // 0..511
  const int wid  = tid >> 6;             // 0..7
  const int lane = tid & 63;
  const int wm = (wid >> 2) * 64;        // 0 / 64
  const int wn = (wid & 3) * 64;         // 0,64,128,192

  // Staging maps (linear LDS dest; inverse-swizzled global source; swizzled reads)
  size_t offA[2]; int ldsA[2];
  size_t offB[4]; int ldsB[4];
#pragma unroll
  for (int j = 0; j < 2; ++j) {
    const int chunk = j * 512 + tid;     // 0..1023 -> A rows 0..127
    const int r  = chunk >> 3;
    const int c8 = (chunk & 7) ^ (r & 7);
    offA[j] = (size_t)(m0 + r) * H_DIM + c8 * 8;
    ldsA[j] = j * 8192 + wid * 1024;
  }
#pragma unroll
  for (int j = 0; j < 4; ++j) {
    const int chunk = j * 512 + tid;     // 0..2047 -> B rows 0..255
    const int r  = chunk >> 3;
    const int c8 = (chunk & 7) ^ (r & 7);
    offB[j] = (size_t)(n0 + r) * H_DIM + c8 * 8;
    ldsB[j] = 16384 + j * 8192 + wid * 1024;
  }

  auto stage = [&](int t) {
    char* dst = lds + ((t & 1) ? A3_BUF : 0);
    const size_t k0 = (size_t)t * 64;
#pragma unroll
    for (int j = 0; j < 2; ++j) gload16(Eb + offA[j] + k0, dst + ldsA[j]);
#pragma unroll
    for (int j = 0; j < 4; ++j) gload16(Wb + offB[j] + k0, dst + ldsB[j]);
  };

  const int fr_row = lane & 15;
  const int fr_k8  = lane >> 4;

  f32x4 acc[4][4];
#pragma unroll
  for (int mf = 0; mf < 4; ++mf)
#pragma unroll
    for (int nf = 0; nf < 4; ++nf) acc[mf][nf] = (f32x4)(0.0f);

  stage(0);                              // 6 loads in flight

  for (int t = 0; t < 16; ++t) {
    if (t < 15) {
      stage(t + 1);                      // +6 loads -> 12 outstanding max
      asm volatile("s_waitcnt vmcnt(6)" ::: "memory");   // tile t landed; t+1 stays in flight
    } else {
      asm volatile("s_waitcnt vmcnt(0)" ::: "memory");
    }
    __builtin_amdgcn_s_barrier();
    asm volatile("" ::: "memory");

    const char* As = lds + ((t & 1) ? A3_BUF : 0);
    const char* Bs = As + 16384;
#pragma unroll
    for (int kh = 0; kh < 2; ++kh) {
      const int kb = kh * 32 + fr_k8 * 8;
      bf16x8 af[4], bfr[4];
#pragma unroll
      for (int mf = 0; mf < 4; ++mf) {
        const int row = wm + mf * 16 + fr_row;               // 0..127
        const int addr = (row * 128 + kb * 2) ^ ((row & 7) << 4);
        af[mf] = *(const bf16x8*)(As + addr);
      }
#pragma unroll
      for (int nf = 0; nf < 4; ++nf) {
        const int row = wn + nf * 16 + fr_row;               // 0..255
        const int addr = (row * 128 + kb * 2) ^ ((row & 7) << 4);
        bfr[nf] = *(const bf16x8*)(Bs + addr);
      }
      __builtin_amdgcn_s_setprio(1);
#pragma unroll
      for (int mf = 0; mf < 4; ++mf)
#pragma unroll
        for (int nf = 0; nf < 4; ++nf)
          acc[mf][nf] = __builtin_amdgcn_mfma_f32_16x16x32_bf16(af[mf], bfr[nf], acc[mf][nf], 0, 0, 0);
      __builtin_amdgcn_s_setprio(0);
    }
    asm volatile("" ::: "memory");
    __builtin_amdgcn_s_barrier();
  }

  float* red = (float*)lds;   // [8 waves][64 rows]

  // Epilogue: tanh(acc + Uh)*v, reduce over this wave's 64 o's.
  // D frag: col = lane&15 (n), row = (lane>>4)*4 + reg (m)
  const int col = lane & 15;
  const int rhi = lane >> 4;
  float uh[4], vv[4];
#pragma unroll
  for (int nf = 0; nf < 4; ++nf) {
    const int o = n0 + wn + nf * 16 + col;
    uh[nf] = Uh[b * H_DIM + o];
    vv[nf] = vw[o];
  }
#pragma unroll
  for (int mf = 0; mf < 4; ++mf) {
    float rs[4];
#pragma unroll
    for (int jj = 0; jj < 4; ++jj) {
      float s = 0.f;
#pragma unroll
      for (int nf = 0; nf < 4; ++nf) {
        const float x = acc[mf][nf][jj] + uh[nf];
        s += fast_tanh(x) * vv[nf];
      }
      rs[jj] = s;
    }
#pragma unroll
    for (int msk = 1; msk < 16; msk <<= 1) {
#pragma unroll
      for (int jj = 0; jj < 4; ++jj) rs[jj] += __shfl_xor(rs[jj], msk, 64);
    }
    if (col == 0) {
#pragma unroll
      for (int jj = 0; jj < 4; ++jj) {
        const int local = mf * 16 + rhi * 4 + jj;   // row within wave's 64
        red[wid * 64 + local] = rs[jj];
      }
    }
  }
  __syncthreads();
  if (tid < 128) {
    const int h4 = (tid >> 6) * 4;       // wave group for this m-half
    const int loc = tid & 63;
    float sum = 0.f;
#pragma unroll
    for (int j = 0; j < 4; ++j) sum += red[(h4 + j) * 64 + loc];
    att_p[(size_t)n_tile * M_DIM + m0 + tid] = sum;
  }
}

// ---------------- K2 (fallback): round-3 gload_lds 128x128 version ----------------
#define BM 128
#define BN 128
#define BK 64
#define KSTEPS (H_DIM / BK)   // 16

__launch_bounds__(256)
__global__ void k_att(const unsigned short* __restrict__ Eb,
                      const unsigned short* __restrict__ Wb,
                      const float* __restrict__ Uh,
                      const float* __restrict__ vw,
                      float* __restrict__ att_p) {
  __shared__ __align__(16) char lds[32 * 1024];
  char* As = lds;
  char* Bs = lds + 16384;
  const int bid = blockIdx.x;
  const int xj = bid & 7;
  const int q  = bid >> 3;
  const int n_tile = q & 7;
  const int m_tile = ((q >> 3) << 3) | xj;
  const int m0 = m_tile * BM;
  const int n0 = n_tile * BN;
  const int b  = m0 >> 10;
  const int tid  = threadIdx.x;
  const int wid  = tid >> 6;
  const int lane = tid & 63;
  const int wm = (wid >> 1) * 64;
  const int wn = (wid & 1) * 64;
  size_t offA[4], offB[4];
  int ldsoff[4];
#pragma unroll
  for (int i = 0; i < 4; ++i) {
    const int chunk = i * 256 + tid;
    const int r  = chunk >> 3;
    const int c8 = (chunk & 7) ^ (r & 7);
    offA[i] = (size_t)(m0 + r) * H_DIM + c8 * 8;
    offB[i] = (size_t)(n0 + r) * H_DIM + c8 * 8;
    ldsoff[i] = i * 4096 + wid * 1024;
  }
  const int fr_row = lane & 15;
  const int fr_k8  = lane >> 4;
  f32x4 acc[4][4];
#pragma unroll
  for (int mf = 0; mf < 4; ++mf)
#pragma unroll
    for (int nf = 0; nf < 4; ++nf) acc[mf][nf] = (f32x4)(0.0f);
  for (int ks = 0; ks < KSTEPS; ++ks) {
    const int k0 = ks * BK;
    __syncthreads();
#pragma unroll
    for (int i = 0; i < 4; ++i) {
      gload16(Eb + offA[i] + k0, As + ldsoff[i]);
      gload16(Wb + offB[i] + k0, Bs + ldsoff[i]);
    }
    __syncthreads();
#pragma unroll
    for (int kh = 0; kh < 2; ++kh) {
      const int kb = kh * 32 + fr_k8 * 8;
      bf16x8 af[4], bfr[4];
#pragma unroll
      for (int mf = 0; mf < 4; ++mf) {
        const int row = wm + mf * 16 + fr_row;
        const int addr = (row * 128 + kb * 2) ^ ((row & 7) << 4);
        af[mf] = *(const bf16x8*)(As + addr);
      }
#pragma unroll
      for (int nf = 0; nf < 4; ++nf) {
        const int row = wn + nf * 16 + fr_row;
        const int addr = (row * 128 + kb * 2) ^ ((row & 7) << 4);
        bfr[nf] = *(const bf16x8*)(Bs + addr);
      }
#pragma unroll
      for (int mf = 0; mf < 4; ++mf)
#pragma unroll
        for (int nf = 0; nf < 4; ++nf)
          acc[mf][nf] = __builtin_amdgcn_mfma_f32_16x16x32_bf16(af[mf], bfr[nf], acc[mf][nf], 0, 0, 0);
    }
  }
  __syncthreads();
  float* red = (float*)lds;
  const int col = lane & 15;
  const int rhi = lane >> 4;
  float uh[4], vv[4];
#pragma unroll
  for (int nf = 0; nf < 4; ++nf) {
    const int o = n0 + wn + nf * 16 + col;
    uh[nf] = Uh[b * H_DIM + o];
    vv[nf] = vw[o];
  }
#pragma unroll
  for (int mf = 0; mf < 4; ++mf) {
    float rs[4];
#pragma unroll
    for (int jj = 0; jj < 4; ++jj) {
      float s = 0.f;
#pragma unroll
      for (int nf = 0; nf < 4; ++nf) {
        const float x = acc[mf][nf][jj] + uh[nf];
        s += fast_tanh(x) * vv[nf];
      }
      rs[jj] = s;
    }
#pragma unroll
    for (int msk = 1; msk < 16; msk <<= 1) {
#pragma unroll
      for (int jj = 0; jj < 4; ++jj) rs[jj] += __shfl_xor(rs[jj], msk, 64);
    }
    if (col == 0) {
#pragma unroll
      for (int jj = 0; jj < 4; ++jj) {
        const int local = mf * 16 + rhi * 4 + jj;
        red[wid * 64 + local] = rs[jj];
      }
    }
  }
  __syncthreads();
  if (tid < 128) {
    const int half = tid >> 6;
    const int loc  = tid & 63;
    const float sum = red[(half * 2) * 64 + loc] + red[(half * 2 + 1) * 64 + loc];
    att_p[(size_t)n_tile * M_DIM + m0 + tid] = sum;
  }
}

// ---------------- K3: softmax over s, per b; nt = number of att partial tiles ----------------
__global__ void k_softmax(const float* __restrict__ att_p, float* __restrict__ alpha, int nt) {
  const int b = blockIdx.x;
  const int tid = threadIdx.x;
  __shared__ float red[8];
  float a[4];
  float mx = -1e30f;
#pragma unroll
  for (int i = 0; i < 4; ++i) {
    const int s = i * 256 + tid;
    float v = 0.f;
    for (int t = 0; t < nt; ++t) v += att_p[(size_t)t * M_DIM + b * S_DIM + s];
    a[i] = v;
    mx = fmaxf(mx, v);
  }
#pragma unroll
  for (int msk = 32; msk >= 1; msk >>= 1) mx = fmaxf(mx, __shfl_xor(mx, msk, 64));
  if ((tid & 63) == 0) red[tid >> 6] = mx;
  __syncthreads();
  mx = fmaxf(fmaxf(red[0], red[1]), fmaxf(red[2], red[3]));
  float sum = 0.f;
#pragma unroll
  for (int i = 0; i < 4; ++i) { a[i] = __expf(a[i] - mx); sum += a[i]; }
#pragma unroll
  for (int msk = 32; msk >= 1; msk >>= 1) sum += __shfl_xor(sum, msk, 64);
  if ((tid & 63) == 0) red[4 + (tid >> 6)] = sum;
  __syncthreads();
  const float inv = 1.f / (red[4] + red[5] + red[6] + red[7]);
#pragma unroll
  for (int i = 0; i < 4; ++i) alpha[b * S_DIM + i * 256 + tid] = a[i] * inv;
}

// ---------------- K4: context partials (bf16 enc, ushort4 vectorized) ----------------
__global__ void k_ctx_bf4(const unsigned short* __restrict__ Eb, const float* __restrict__ alpha,
                          float* __restrict__ ctx_p) {
  const int bid = blockIdx.x;           // 128 = b(32) * sq(4)
  const int b  = bid >> 2;
  const int sq = bid & 3;
  const int h = threadIdx.x * 4;        // 0..1020
  const float* ap = &alpha[b * S_DIM + sq * 256];
  const unsigned short* ep = Eb + (size_t)b * S_DIM * H_DIM + (size_t)(sq * 256) * H_DIM + h;
  float4 acc = make_float4(0.f, 0.f, 0.f, 0.f);
  for (int s = 0; s < 256; ++s) {
    const float a = ap[s];
    ushort4 v = *(const ushort4*)(ep + (size_t)s * H_DIM);
    acc.x += a * bf2f(v.x);
    acc.y += a * bf2f(v.y);
    acc.z += a * bf2f(v.z);
    acc.w += a * bf2f(v.w);
  }
  *(float4*)&ctx_p[(size_t)sq * (B_DIM * H_DIM) + b * H_DIM + h] = acc;
}

// ---------------- K5: reduce context partials -> d_out ----------------
__global__ void k_ctx_reduce(const float* __restrict__ ctx_p, float* __restrict__ ctx) {
  const int i = blockIdx.x * 256 + threadIdx.x;
  ctx[i] = ctx_p[i] + ctx_p[32768 + i] + ctx_p[65536 + i] + ctx_p[98304 + i];
}

extern "C" void kernel_launch(void* const* d_in, const int* in_sizes, int n_in,
                              void* d_out, int out_size, void* d_ws, size_t ws_size,
                              hipStream_t stream) {
  (void)in_sizes; (void)n_in; (void)out_size;
  const float* dh  = (const float*)d_in[0];
  const float* enc = (const float*)d_in[1];
  const float* Uw  = (const float*)d_in[2];
  const float* Ww  = (const float*)d_in[3];
  const float* vw  = (const float*)d_in[4];
  float* ctx_out = (float*)d_out;                 // [32,1024]
  float* alpha   = (float*)d_out + M_DIM;         // [32,1024]

  char* ws = (char*)d_ws;
  const size_t EB_BYTES = (size_t)M_DIM * H_DIM * 2;            // 64 MiB
  const size_t NEED = EB_BYTES + (2u << 20) + (128u << 10) + (1u << 20) + (512u << 10);

  unsigned short* Eb = (unsigned short*)ws;
  unsigned short* Wb = (unsigned short*)(ws + EB_BYTES);
  float* Uh    = (float*)(ws + EB_BYTES + (2u << 20));
  float* att_p = (float*)(ws + EB_BYTES + (2u << 20) + (128u << 10));
  float* ctx_p = (float*)(ws + EB_BYTES + (2u << 20) + (128u << 10) + (1u << 20));

  if (ws_size >= NEED) {
    k_convert_w<<<1024, 256, 0, stream>>>(Ww, Wb);
    k_convert_enc<<<2048, 256, 0, stream>>>(enc, Eb);
    k_uh<<<256, 256, 0, stream>>>(dh, Uw, Uh);
    k_att3<<<1024, 512, 0, stream>>>(Eb, Wb, Uh, vw, att_p);
    k_softmax<<<32, 256, 0, stream>>>(att_p, alpha, NT_FAST);
    k_ctx_bf4<<<128, 256, 0, stream>>>(Eb, alpha, ctx_p);
    k_ctx_reduce<<<128, 256, 0, stream>>>(ctx_p, ctx_out);
  } else {
    // fallback (should not trigger given prior rounds): 128x128 path
    k_convert_w<<<1024, 256, 0, stream>>>(Ww, Wb);
    k_convert_enc<<<2048, 256, 0, stream>>>(enc, Eb);
    k_uh<<<256, 256, 0, stream>>>(dh, Uw, Uh);
    k_att<<<2048, 256, 0, stream>>>(Eb, Wb, Uh, vw, att_p);
    k_softmax<<<32, 256, 0, stream>>>(att_p, alpha, 8);
    k_ctx_bf4<<<128, 256, 0, stream>>>(Eb, alpha, ctx_p);
    k_ctx_reduce<<<128, 256, 0, stream>>>(ctx_p, ctx_out);
  }
}

// Round 5
// 169.728 us; speedup vs baseline: 1.0875x; 1.0023x over previous
//
#include <hip/hip_runtime.h>
#include <hip/hip_bf16.h>
#include <cstdint>
#include <cstddef>

#define B_DIM 32
#define S_DIM 1024
#define H_DIM 1024
#define M_DIM (B_DIM * S_DIM)   // 32768

typedef __attribute__((ext_vector_type(8))) short bf16x8;
typedef __attribute__((ext_vector_type(4))) float f32x4;
typedef __attribute__((ext_vector_type(4))) int int4v;

// round-to-nearest-even fp32 -> bf16 (bit trick; no NaN inputs here)
static __device__ __forceinline__ unsigned short f2bf(float f) {
  unsigned u = __float_as_uint(f);
  u = (u + 0x7FFFu + ((u >> 16) & 1u)) >> 16;
  return (unsigned short)u;
}
static __device__ __forceinline__ float bf2f(unsigned short u) {
  return __uint_as_float(((unsigned)u) << 16);
}
// exact identity tanh(x) = 1 - 2/(exp(2x)+1); __expf err ~2ulp, saturates correctly
static __device__ __forceinline__ float fast_tanh(float x) {
  return 1.f - 2.f / (__expf(2.f * x) + 1.f);
}

// async global(16B/lane) -> LDS, wave-uniform LDS base, per-lane global addr
static __device__ __forceinline__ void gload16(const unsigned short* g, char* l) {
  __builtin_amdgcn_global_load_lds(
      (const __attribute__((address_space(1))) unsigned int*)g,
      (__attribute__((address_space(3))) unsigned int*)l, 16, 0, 0);
}

// ---------------- K0b: enc fp32 -> bf16 ----------------
__global__ void k_convert_enc(const float* __restrict__ E, unsigned short* __restrict__ Eb) {
  const int n8 = M_DIM * (H_DIM / 8);              // 4,194,304 chunks
  const int stride = gridDim.x * 256;
  for (int idx = blockIdx.x * 256 + threadIdx.x; idx < n8; idx += stride) {
    const float4* gp = (const float4*)(E + (size_t)idx * 8);
    float4 lo = gp[0], hi = gp[1];
    bf16x8 w;
    w[0] = (short)f2bf(lo.x); w[1] = (short)f2bf(lo.y);
    w[2] = (short)f2bf(lo.z); w[3] = (short)f2bf(lo.w);
    w[4] = (short)f2bf(hi.x); w[5] = (short)f2bf(hi.y);
    w[6] = (short)f2bf(hi.z); w[7] = (short)f2bf(hi.w);
    *(bf16x8*)(Eb + (size_t)idx * 8) = w;
  }
}

// ---------------- K_prep: blocks 0..1023 convert W_w -> bf16; blocks 1024..1279 compute U_h ----------------
__global__ void k_prep(const float* __restrict__ W, unsigned short* __restrict__ Wb,
                       const float* __restrict__ dh, const float* __restrict__ Uw,
                       float* __restrict__ Uh) {
  if (blockIdx.x < 1024) {
    const int idx = blockIdx.x * 256 + threadIdx.x;   // 0 .. 262143 (1M/4)
    float4 v = ((const float4*)W)[idx];
    ushort4 o;
    o.x = f2bf(v.x); o.y = f2bf(v.y); o.z = f2bf(v.z); o.w = f2bf(v.w);
    ((ushort4*)Wb)[idx] = o;
  } else {
    const int wave = threadIdx.x >> 6;
    const int lane = threadIdx.x & 63;
    const int o = (blockIdx.x - 1024) * 4 + wave;     // 0..1023
    float uw[16];
#pragma unroll
    for (int k = 0; k < 16; ++k) uw[k] = Uw[o * H_DIM + k * 64 + lane];
    for (int b = 0; b < B_DIM; ++b) {
      float acc = 0.f;
#pragma unroll
      for (int k = 0; k < 16; ++k) acc += uw[k] * dh[b * H_DIM + k * 64 + lane];
#pragma unroll
      for (int msk = 32; msk >= 1; msk >>= 1) acc += __shfl_xor(acc, msk, 64);
      if (lane == 0) Uh[b * H_DIM + o] = acc;
    }
  }
}

// ---------------- K2 (fast): 2-deep counted-vmcnt pipelined fused att GEMM ----------------
// BM=128, BN=256, BK=64. 512 threads = 8 waves (2M x 4N), per-wave 64x64 tile.
// LDS: 3 buffers x (A 16KB + B 32KB) = 144KB. 1 block/CU.
#define A3_BM 128
#define A3_BN 256
#define A3_BUF 49152
#define NT_FAST 4      // n_tiles

__launch_bounds__(512, 2)
__global__ void k_att3(const unsigned short* __restrict__ Eb,
                       const unsigned short* __restrict__ Wb,
                       const float* __restrict__ Uh,
                       const float* __restrict__ vw,
                       float* __restrict__ att_p) {
  __shared__ __align__(16) char lds[3 * A3_BUF];   // 144 KB

  // XCD-friendly: blocks with same (bid&7) sit on one XCD
  const int bid = blockIdx.x;            // 0..1023
  const int xj = bid & 7;
  const int q  = bid >> 3;               // 0..127
  const int n_tile = q & 3;              // 0..3
  const int m_tile = ((q >> 2) << 3) | xj;   // 0..255, bijective
  const int m0 = m_tile * A3_BM;
  const int n0 = n_tile * A3_BN;
  const int b  = m0 >> 10;

  const int tid  = threadIdx.x;          // 0..511
  const int wid  = tid >> 6;             // 0..7
  const int lane = tid & 63;
  const int wm = (wid >> 2) * 64;        // 0 / 64
  const int wn = (wid & 3) * 64;         // 0,64,128,192

  // Staging maps (linear LDS dest; inverse-swizzled global source; swizzled reads)
  size_t offA[2]; int ldsA[2];
  size_t offB[4]; int ldsB[4];
#pragma unroll
  for (int j = 0; j < 2; ++j) {
    const int chunk = j * 512 + tid;     // 0..1023 -> A rows 0..127
    const int r  = chunk >> 3;
    const int c8 = (chunk & 7) ^ (r & 7);
    offA[j] = (size_t)(m0 + r) * H_DIM + c8 * 8;
    ldsA[j] = j * 8192 + wid * 1024;
  }
#pragma unroll
  for (int j = 0; j < 4; ++j) {
    const int chunk = j * 512 + tid;     // 0..2047 -> B rows 0..255
    const int r  = chunk >> 3;
    const int c8 = (chunk & 7) ^ (r & 7);
    offB[j] = (size_t)(n0 + r) * H_DIM + c8 * 8;
    ldsB[j] = 16384 + j * 8192 + wid * 1024;
  }

  auto stage = [&](int t) {
    char* dst = lds + (t % 3) * A3_BUF;
    const size_t k0 = (size_t)t * 64;
#pragma unroll
    for (int j = 0; j < 2; ++j) gload16(Eb + offA[j] + k0, dst + ldsA[j]);
#pragma unroll
    for (int j = 0; j < 4; ++j) gload16(Wb + offB[j] + k0, dst + ldsB[j]);
  };

  const int fr_row = lane & 15;
  const int fr_k8  = lane >> 4;

  f32x4 acc[4][4];
#pragma unroll
  for (int mf = 0; mf < 4; ++mf)
#pragma unroll
    for (int nf = 0; nf < 4; ++nf) acc[mf][nf] = (f32x4)(0.0f);

  stage(0);
  stage(1);                              // 12 loads in flight

  for (int t = 0; t < 16; ++t) {
    if (t < 14) {
      stage(t + 2);                      // +6 loads -> up to 18 outstanding
      asm volatile("s_waitcnt vmcnt(12)" ::: "memory");  // tile t landed; t+1,t+2 in flight
    } else if (t == 14) {
      asm volatile("s_waitcnt vmcnt(6)" ::: "memory");   // tile 14 landed; 15 in flight
    } else {
      asm volatile("s_waitcnt vmcnt(0)" ::: "memory");
    }
    __builtin_amdgcn_s_barrier();
    asm volatile("" ::: "memory");

    const char* As = lds + (t % 3) * A3_BUF;
    const char* Bs = As + 16384;
#pragma unroll
    for (int kh = 0; kh < 2; ++kh) {
      const int kb = kh * 32 + fr_k8 * 8;
      bf16x8 af[4], bfr[4];
#pragma unroll
      for (int mf = 0; mf < 4; ++mf) {
        const int row = wm + mf * 16 + fr_row;               // 0..127
        const int addr = (row * 128 + kb * 2) ^ ((row & 7) << 4);
        af[mf] = *(const bf16x8*)(As + addr);
      }
#pragma unroll
      for (int nf = 0; nf < 4; ++nf) {
        const int row = wn + nf * 16 + fr_row;               // 0..255
        const int addr = (row * 128 + kb * 2) ^ ((row & 7) << 4);
        bfr[nf] = *(const bf16x8*)(Bs + addr);
      }
      __builtin_amdgcn_s_setprio(1);
#pragma unroll
      for (int mf = 0; mf < 4; ++mf)
#pragma unroll
        for (int nf = 0; nf < 4; ++nf)
          acc[mf][nf] = __builtin_amdgcn_mfma_f32_16x16x32_bf16(af[mf], bfr[nf], acc[mf][nf], 0, 0, 0);
      __builtin_amdgcn_s_setprio(0);
    }
    asm volatile("" ::: "memory");
    __builtin_amdgcn_s_barrier();
  }

  float* red = (float*)lds;   // [8 waves][64 rows]

  // Epilogue: tanh(acc + Uh)*v, reduce over this wave's 64 o's.
  // D frag: col = lane&15 (n), row = (lane>>4)*4 + reg (m)
  const int col = lane & 15;
  const int rhi = lane >> 4;
  float uh[4], vv[4];
#pragma unroll
  for (int nf = 0; nf < 4; ++nf) {
    const int o = n0 + wn + nf * 16 + col;
    uh[nf] = Uh[b * H_DIM + o];
    vv[nf] = vw[o];
  }
#pragma unroll
  for (int mf = 0; mf < 4; ++mf) {
    float rs[4];
#pragma unroll
    for (int jj = 0; jj < 4; ++jj) {
      float s = 0.f;
#pragma unroll
      for (int nf = 0; nf < 4; ++nf) {
        const float x = acc[mf][nf][jj] + uh[nf];
        s += fast_tanh(x) * vv[nf];
      }
      rs[jj] = s;
    }
#pragma unroll
    for (int msk = 1; msk < 16; msk <<= 1) {
#pragma unroll
      for (int jj = 0; jj < 4; ++jj) rs[jj] += __shfl_xor(rs[jj], msk, 64);
    }
    if (col == 0) {
#pragma unroll
      for (int jj = 0; jj < 4; ++jj) {
        const int local = mf * 16 + rhi * 4 + jj;   // row within wave's 64
        red[wid * 64 + local] = rs[jj];
      }
    }
  }
  __syncthreads();
  if (tid < 128) {
    const int h4 = (tid >> 6) * 4;       // wave group for this m-half
    const int loc = tid & 63;
    float sum = 0.f;
#pragma unroll
    for (int j = 0; j < 4; ++j) sum += red[(h4 + j) * 64 + loc];
    att_p[(size_t)n_tile * M_DIM + m0 + tid] = sum;
  }
}

// ---------------- K3: softmax over s, per b; nt = number of att partial tiles ----------------
__global__ void k_softmax(const float* __restrict__ att_p, float* __restrict__ alpha, int nt) {
  const int b = blockIdx.x;
  const int tid = threadIdx.x;
  __shared__ float red[8];
  float a[4];
  float mx = -1e30f;
#pragma unroll
  for (int i = 0; i < 4; ++i) {
    const int s = i * 256 + tid;
    float v = 0.f;
    for (int t = 0; t < nt; ++t) v += att_p[(size_t)t * M_DIM + b * S_DIM + s];
    a[i] = v;
    mx = fmaxf(mx, v);
  }
#pragma unroll
  for (int msk = 32; msk >= 1; msk >>= 1) mx = fmaxf(mx, __shfl_xor(mx, msk, 64));
  if ((tid & 63) == 0) red[tid >> 6] = mx;
  __syncthreads();
  mx = fmaxf(fmaxf(red[0], red[1]), fmaxf(red[2], red[3]));
  float sum = 0.f;
#pragma unroll
  for (int i = 0; i < 4; ++i) { a[i] = __expf(a[i] - mx); sum += a[i]; }
#pragma unroll
  for (int msk = 32; msk >= 1; msk >>= 1) sum += __shfl_xor(sum, msk, 64);
  if ((tid & 63) == 0) red[4 + (tid >> 6)] = sum;
  __syncthreads();
  const float inv = 1.f / (red[4] + red[5] + red[6] + red[7]);
#pragma unroll
  for (int i = 0; i < 4; ++i) alpha[b * S_DIM + i * 256 + tid] = a[i] * inv;
}

// ---------------- K4: context partials (bf16 enc, ushort4 vectorized) ----------------
__global__ void k_ctx_bf4(const unsigned short* __restrict__ Eb, const float* __restrict__ alpha,
                          float* __restrict__ ctx_p) {
  const int bid = blockIdx.x;           // 128 = b(32) * sq(4)
  const int b  = bid >> 2;
  const int sq = bid & 3;
  const int h = threadIdx.x * 4;        // 0..1020
  const float* ap = &alpha[b * S_DIM + sq * 256];
  const unsigned short* ep = Eb + (size_t)b * S_DIM * H_DIM + (size_t)(sq * 256) * H_DIM + h;
  float4 acc = make_float4(0.f, 0.f, 0.f, 0.f);
  for (int s = 0; s < 256; ++s) {
    const float a = ap[s];
    ushort4 v = *(const ushort4*)(ep + (size_t)s * H_DIM);
    acc.x += a * bf2f(v.x);
    acc.y += a * bf2f(v.y);
    acc.z += a * bf2f(v.z);
    acc.w += a * bf2f(v.w);
  }
  *(float4*)&ctx_p[(size_t)sq * (B_DIM * H_DIM) + b * H_DIM + h] = acc;
}

// ---------------- K5: reduce context partials -> d_out ----------------
__global__ void k_ctx_reduce(const float* __restrict__ ctx_p, float* __restrict__ ctx) {
  const int i = blockIdx.x * 256 + threadIdx.x;
  ctx[i] = ctx_p[i] + ctx_p[32768 + i] + ctx_p[65536 + i] + ctx_p[98304 + i];
}

extern "C" void kernel_launch(void* const* d_in, const int* in_sizes, int n_in,
                              void* d_out, int out_size, void* d_ws, size_t ws_size,
                              hipStream_t stream) {
  (void)in_sizes; (void)n_in; (void)out_size; (void)ws_size;
  const float* dh  = (const float*)d_in[0];
  const float* enc = (const float*)d_in[1];
  const float* Uw  = (const float*)d_in[2];
  const float* Ww  = (const float*)d_in[3];
  const float* vw  = (const float*)d_in[4];
  float* ctx_out = (float*)d_out;                 // [32,1024]
  float* alpha   = (float*)d_out + M_DIM;         // [32,1024]

  char* ws = (char*)d_ws;
  const size_t EB_BYTES = (size_t)M_DIM * H_DIM * 2;            // 64 MiB

  unsigned short* Eb = (unsigned short*)ws;
  unsigned short* Wb = (unsigned short*)(ws + EB_BYTES);
  float* Uh    = (float*)(ws + EB_BYTES + (2u << 20));
  float* att_p = (float*)(ws + EB_BYTES + (2u << 20) + (128u << 10));
  float* ctx_p = (float*)(ws + EB_BYTES + (2u << 20) + (128u << 10) + (1u << 20));

  k_convert_enc<<<2048, 256, 0, stream>>>(enc, Eb);
  k_prep<<<1280, 256, 0, stream>>>(Ww, Wb, dh, Uw, Uh);
  k_att3<<<1024, 512, 0, stream>>>(Eb, Wb, Uh, vw, att_p);
  k_softmax<<<32, 256, 0, stream>>>(att_p, alpha, NT_FAST);
  k_ctx_bf4<<<128, 256, 0, stream>>>(Eb, alpha, ctx_p);
  k_ctx_reduce<<<128, 256, 0, stream>>>(ctx_p, ctx_out);
}

// Round 6
// 151.494 us; speedup vs baseline: 1.2184x; 1.1204x over previous
//
#include <hip/hip_runtime.h>
#include <hip/hip_bf16.h>
#include <cstdint>
#include <cstddef>

#define B_DIM 32
#define S_DIM 1024
#define H_DIM 1024
#define M_DIM (B_DIM * S_DIM)   // 32768

typedef __attribute__((ext_vector_type(8))) short bf16x8;
typedef __attribute__((ext_vector_type(4))) float f32x4;

// round-to-nearest-even fp32 -> bf16 (bit trick; no NaN inputs here)
static __device__ __forceinline__ unsigned short f2bf(float f) {
  unsigned u = __float_as_uint(f);
  u = (u + 0x7FFFu + ((u >> 16) & 1u)) >> 16;
  return (unsigned short)u;
}
static __device__ __forceinline__ float bf2f(unsigned short u) {
  return __uint_as_float(((unsigned)u) << 16);
}
// exact identity tanh(x) = 1 - 2/(exp(2x)+1)
static __device__ __forceinline__ float fast_tanh(float x) {
  return 1.f - 2.f / (__expf(2.f * x) + 1.f);
}

// async global(16B/lane) -> LDS, wave-uniform LDS base, per-lane global addr
static __device__ __forceinline__ void gload16(const unsigned short* g, char* l) {
  __builtin_amdgcn_global_load_lds(
      (const __attribute__((address_space(1))) unsigned int*)g,
      (__attribute__((address_space(3))) unsigned int*)l, 16, 0, 0);
}

// ---------------- K_prep_all: enc->bf16 (blocks 0..2047), W->bf16 (2048..3071), U_h (3072..3327) ----------------
__global__ void k_prep_all(const float* __restrict__ E, unsigned short* __restrict__ Eb,
                           const float* __restrict__ W, unsigned short* __restrict__ Wb,
                           const float* __restrict__ dh, const float* __restrict__ Uw,
                           float* __restrict__ Uh) {
  const int bid = blockIdx.x;
  if (bid < 2048) {
    const int n8 = M_DIM * (H_DIM / 8);              // 4,194,304 chunks
    const int stride = 2048 * 256;
    for (int idx = bid * 256 + threadIdx.x; idx < n8; idx += stride) {
      const float4* gp = (const float4*)(E + (size_t)idx * 8);
      float4 lo = gp[0], hi = gp[1];
      bf16x8 w;
      w[0] = (short)f2bf(lo.x); w[1] = (short)f2bf(lo.y);
      w[2] = (short)f2bf(lo.z); w[3] = (short)f2bf(lo.w);
      w[4] = (short)f2bf(hi.x); w[5] = (short)f2bf(hi.y);
      w[6] = (short)f2bf(hi.z); w[7] = (short)f2bf(hi.w);
      *(bf16x8*)(Eb + (size_t)idx * 8) = w;
    }
  } else if (bid < 3072) {
    const int idx = (bid - 2048) * 256 + threadIdx.x;  // 0 .. 262143
    float4 v = ((const float4*)W)[idx];
    ushort4 o;
    o.x = f2bf(v.x); o.y = f2bf(v.y); o.z = f2bf(v.z); o.w = f2bf(v.w);
    ((ushort4*)Wb)[idx] = o;
  } else {
    const int wave = threadIdx.x >> 6;
    const int lane = threadIdx.x & 63;
    const int o = (bid - 3072) * 4 + wave;             // 0..1023
    float uw[16];
#pragma unroll
    for (int k = 0; k < 16; ++k) uw[k] = Uw[o * H_DIM + k * 64 + lane];
    for (int b = 0; b < B_DIM; ++b) {
      float acc = 0.f;
#pragma unroll
      for (int k = 0; k < 16; ++k) acc += uw[k] * dh[b * H_DIM + k * 64 + lane];
#pragma unroll
      for (int msk = 32; msk >= 1; msk >>= 1) acc += __shfl_xor(acc, msk, 64);
      if (lane == 0) Uh[b * H_DIM + o] = acc;
    }
  }
}

// ---------------- K2: phase-split counted-vmcnt fused att GEMM ----------------
// BM=128, BN=256, BK=64. 512 threads = 8 waves (2M x 4N), per-wave 64x64 tile.
// LDS: 3 buffers x (A 16KB + B 32KB) = 144KB. Prefetch distance 2 K-tiles.
#define A3_BM 128
#define A3_BN 256
#define A3_BUF 49152
#define NT_FAST 4      // n_tiles

__launch_bounds__(512, 2)
__global__ void k_att4(const unsigned short* __restrict__ Eb,
                       const unsigned short* __restrict__ Wb,
                       const float* __restrict__ Uh,
                       const float* __restrict__ vw,
                       float* __restrict__ att_p) {
  __shared__ __align__(16) char lds[3 * A3_BUF];   // 144 KB

  // XCD-friendly: blocks with same (bid&7) sit on one XCD
  const int bid = blockIdx.x;            // 0..1023
  const int xj = bid & 7;
  const int q  = bid >> 3;               // 0..127
  const int n_tile = q & 3;              // 0..3
  const int m_tile = ((q >> 2) << 3) | xj;   // 0..255, bijective
  const int m0 = m_tile * A3_BM;
  const int n0 = n_tile * A3_BN;
  const int b  = m0 >> 10;

  const int tid  = threadIdx.x;          // 0..511
  const int wid  = tid >> 6;             // 0..7
  const int lane = tid & 63;
  const int wm = (wid >> 2) * 64;        // 0 / 64
  const int wn = (wid & 3) * 64;         // 0,64,128,192

  // Staging maps (linear LDS dest; inverse-swizzled global source; swizzled reads)
  size_t offA[2]; int ldsA[2];
  size_t offB[4]; int ldsB[4];
#pragma unroll
  for (int j = 0; j < 2; ++j) {
    const int chunk = j * 512 + tid;     // A rows 0..127
    const int r  = chunk >> 3;
    const int c8 = (chunk & 7) ^ (r & 7);
    offA[j] = (size_t)(m0 + r) * H_DIM + c8 * 8;
    ldsA[j] = j * 8192 + wid * 1024;
  }
#pragma unroll
  for (int j = 0; j < 4; ++j) {
    const int chunk = j * 512 + tid;     // B rows 0..255
    const int r  = chunk >> 3;
    const int c8 = (chunk & 7) ^ (r & 7);
    offB[j] = (size_t)(n0 + r) * H_DIM + c8 * 8;
    ldsB[j] = 16384 + j * 8192 + wid * 1024;
  }

  auto stage_all = [&](int t) {          // prologue only: 6 loads
    char* dst = lds + (t % 3) * A3_BUF;
    const size_t k0 = (size_t)t * 64;
#pragma unroll
    for (int j = 0; j < 2; ++j) gload16(Eb + offA[j] + k0, dst + ldsA[j]);
#pragma unroll
    for (int j = 0; j < 4; ++j) gload16(Wb + offB[j] + k0, dst + ldsB[j]);
  };

  const int fr_row = lane & 15;
  const int fr_k8  = lane >> 4;

  f32x4 acc[4][4];
#pragma unroll
  for (int mf = 0; mf < 4; ++mf)
#pragma unroll
    for (int nf = 0; nf < 4; ++nf) acc[mf][nf] = (f32x4)(0.0f);

  stage_all(0);
  stage_all(1);                          // 12 loads in flight

  for (int t = 0; t < 16; ++t) {
    // Ledger: stages for t+2 are issued strictly between this wait and the next
    // (asm memory clobbers pin them). Outstanding here = (t+1)'s 6 (+ maybe t's
    // unlanded) -> vmcnt(6) guarantees tile t fully landed, t+1 stays in flight.
    if (t < 15) asm volatile("s_waitcnt vmcnt(6)" ::: "memory");
    else        asm volatile("s_waitcnt vmcnt(0)" ::: "memory");
    __builtin_amdgcn_s_barrier();        // other waves' DMA for tile t visible

    const char* As = lds + (t % 3) * A3_BUF;
    const char* Bs = As + 16384;
    char* dst = lds + ((t + 2) % 3) * A3_BUF;   // != buf(t), != buf(t+1)
    const size_t k2 = (size_t)(t + 2) * 64;
    const bool doStage = (t <= 13);

#pragma unroll
    for (int kh = 0; kh < 2; ++kh) {
      const int kb = kh * 32 + fr_k8 * 8;
      bf16x8 af[4], bfr[4];
#pragma unroll
      for (int mf = 0; mf < 4; ++mf) {
        const int row = wm + mf * 16 + fr_row;               // 0..127
        const int addr = (row * 128 + kb * 2) ^ ((row & 7) << 4);
        af[mf] = *(const bf16x8*)(As + addr);
      }
#pragma unroll
      for (int nf = 0; nf < 4; ++nf) {
        const int row = wn + nf * 16 + fr_row;               // 0..255
        const int addr = (row * 128 + kb * 2) ^ ((row & 7) << 4);
        bfr[nf] = *(const bf16x8*)(Bs + addr);
      }
      if (doStage) {
        if (kh == 0) {
          gload16(Eb + offA[0] + k2, dst + ldsA[0]);
          gload16(Eb + offA[1] + k2, dst + ldsA[1]);
          gload16(Wb + offB[0] + k2, dst + ldsB[0]);
        } else {
          gload16(Wb + offB[1] + k2, dst + ldsB[1]);
          gload16(Wb + offB[2] + k2, dst + ldsB[2]);
          gload16(Wb + offB[3] + k2, dst + ldsB[3]);
        }
      }
      __builtin_amdgcn_s_barrier();      // align waves; lgkm handled by compiler
      __builtin_amdgcn_s_setprio(1);
#pragma unroll
      for (int mf = 0; mf < 4; ++mf)
#pragma unroll
        for (int nf = 0; nf < 4; ++nf)
          acc[mf][nf] = __builtin_amdgcn_mfma_f32_16x16x32_bf16(af[mf], bfr[nf], acc[mf][nf], 0, 0, 0);
      __builtin_amdgcn_s_setprio(0);
      __builtin_amdgcn_s_barrier();
    }
  }

  float* red = (float*)lds;   // [8 waves][64 rows]

  // Epilogue: tanh(acc + Uh)*v, reduce over this wave's 64 o's.
  // D frag: col = lane&15 (n), row = (lane>>4)*4 + reg (m)
  const int col = lane & 15;
  const int rhi = lane >> 4;
  float uh[4], vv[4];
#pragma unroll
  for (int nf = 0; nf < 4; ++nf) {
    const int o = n0 + wn + nf * 16 + col;
    uh[nf] = Uh[b * H_DIM + o];
    vv[nf] = vw[o];
  }
#pragma unroll
  for (int mf = 0; mf < 4; ++mf) {
    float rs[4];
#pragma unroll
    for (int jj = 0; jj < 4; ++jj) {
      float s = 0.f;
#pragma unroll
      for (int nf = 0; nf < 4; ++nf) {
        const float x = acc[mf][nf][jj] + uh[nf];
        s += fast_tanh(x) * vv[nf];
      }
      rs[jj] = s;
    }
#pragma unroll
    for (int msk = 1; msk < 16; msk <<= 1) {
#pragma unroll
      for (int jj = 0; jj < 4; ++jj) rs[jj] += __shfl_xor(rs[jj], msk, 64);
    }
    if (col == 0) {
#pragma unroll
      for (int jj = 0; jj < 4; ++jj) {
        const int local = mf * 16 + rhi * 4 + jj;   // row within wave's 64
        red[wid * 64 + local] = rs[jj];
      }
    }
  }
  __syncthreads();
  if (tid < 128) {
    const int h4 = (tid >> 6) * 4;       // wave group for this m-half
    const int loc = tid & 63;
    float sum = 0.f;
#pragma unroll
    for (int j = 0; j < 4; ++j) sum += red[(h4 + j) * 64 + loc];
    att_p[(size_t)n_tile * M_DIM + m0 + tid] = sum;
  }
}

// ---------------- K3: fused softmax + context partials ----------------
// 128 blocks = b(32) x sq(4). Each block recomputes row-b softmax locally
// (16 KB redundant att_p read), sq==0 writes alpha, all compute ctx partials.
__global__ void k_ctx_sm(const unsigned short* __restrict__ Eb,
                         const float* __restrict__ att_p,
                         float* __restrict__ alpha_out,
                         float* __restrict__ ctx_p) {
  const int bid = blockIdx.x;
  const int b  = bid >> 2;
  const int sq = bid & 3;
  const int tid = threadIdx.x;
  __shared__ float red[8];
  __shared__ float qa[256];

  float a[4];
  float mx = -1e30f;
#pragma unroll
  for (int i = 0; i < 4; ++i) {
    const int s = i * 256 + tid;
    float v = 0.f;
#pragma unroll
    for (int t = 0; t < NT_FAST; ++t) v += att_p[(size_t)t * M_DIM + b * S_DIM + s];
    a[i] = v;
    mx = fmaxf(mx, v);
  }
#pragma unroll
  for (int msk = 32; msk >= 1; msk >>= 1) mx = fmaxf(mx, __shfl_xor(mx, msk, 64));
  if ((tid & 63) == 0) red[tid >> 6] = mx;
  __syncthreads();
  mx = fmaxf(fmaxf(red[0], red[1]), fmaxf(red[2], red[3]));
  float sum = 0.f;
#pragma unroll
  for (int i = 0; i < 4; ++i) { a[i] = __expf(a[i] - mx); sum += a[i]; }
#pragma unroll
  for (int msk = 32; msk >= 1; msk >>= 1) sum += __shfl_xor(sum, msk, 64);
  if ((tid & 63) == 0) red[4 + (tid >> 6)] = sum;
  __syncthreads();
  const float inv = 1.f / (red[4] + red[5] + red[6] + red[7]);
  if (sq == 0) {
#pragma unroll
    for (int i = 0; i < 4; ++i) alpha_out[b * S_DIM + i * 256 + tid] = a[i] * inv;
  }
  qa[tid] = a[sq] * inv;                  // alpha for s = sq*256 + tid
  __syncthreads();

  const int h = tid * 4;                  // 0..1020
  const unsigned short* ep = Eb + (size_t)b * S_DIM * H_DIM + (size_t)(sq * 256) * H_DIM + h;
  float4 acc = make_float4(0.f, 0.f, 0.f, 0.f);
  for (int s = 0; s < 256; ++s) {
    const float al = qa[s];
    ushort4 v = *(const ushort4*)(ep + (size_t)s * H_DIM);
    acc.x += al * bf2f(v.x);
    acc.y += al * bf2f(v.y);
    acc.z += al * bf2f(v.z);
    acc.w += al * bf2f(v.w);
  }
  *(float4*)&ctx_p[(size_t)sq * (B_DIM * H_DIM) + b * H_DIM + h] = acc;
}

// ---------------- K5: reduce context partials -> d_out ----------------
__global__ void k_ctx_reduce(const float* __restrict__ ctx_p, float* __restrict__ ctx) {
  const int i = blockIdx.x * 256 + threadIdx.x;
  ctx[i] = ctx_p[i] + ctx_p[32768 + i] + ctx_p[65536 + i] + ctx_p[98304 + i];
}

extern "C" void kernel_launch(void* const* d_in, const int* in_sizes, int n_in,
                              void* d_out, int out_size, void* d_ws, size_t ws_size,
                              hipStream_t stream) {
  (void)in_sizes; (void)n_in; (void)out_size; (void)ws_size;
  const float* dh  = (const float*)d_in[0];
  const float* enc = (const float*)d_in[1];
  const float* Uw  = (const float*)d_in[2];
  const float* Ww  = (const float*)d_in[3];
  const float* vw  = (const float*)d_in[4];
  float* ctx_out = (float*)d_out;                 // [32,1024]
  float* alpha   = (float*)d_out + M_DIM;         // [32,1024]

  char* ws = (char*)d_ws;
  const size_t EB_BYTES = (size_t)M_DIM * H_DIM * 2;            // 64 MiB

  unsigned short* Eb = (unsigned short*)ws;
  unsigned short* Wb = (unsigned short*)(ws + EB_BYTES);
  float* Uh    = (float*)(ws + EB_BYTES + (2u << 20));
  float* att_p = (float*)(ws + EB_BYTES + (2u << 20) + (128u << 10));
  float* ctx_p = (float*)(ws + EB_BYTES + (2u << 20) + (128u << 10) + (1u << 20));

  k_prep_all<<<3328, 256, 0, stream>>>(enc, Eb, Ww, Wb, dh, Uw, Uh);
  k_att4<<<1024, 512, 0, stream>>>(Eb, Wb, Uh, vw, att_p);
  k_ctx_sm<<<128, 256, 0, stream>>>(Eb, att_p, alpha, ctx_p);
  k_ctx_reduce<<<128, 256, 0, stream>>>(ctx_p, ctx_out);
}

// Round 7
// 148.641 us; speedup vs baseline: 1.2417x; 1.0192x over previous
//
#include <hip/hip_runtime.h>
#include <hip/hip_bf16.h>
#include <cstdint>
#include <cstddef>

#define B_DIM 32
#define S_DIM 1024
#define H_DIM 1024
#define M_DIM (B_DIM * S_DIM)   // 32768

typedef __attribute__((ext_vector_type(8))) short bf16x8;
typedef __attribute__((ext_vector_type(4))) float f32x4;

// round-to-nearest-even fp32 -> bf16 (bit trick; no NaN inputs here)
static __device__ __forceinline__ unsigned short f2bf(float f) {
  unsigned u = __float_as_uint(f);
  u = (u + 0x7FFFu + ((u >> 16) & 1u)) >> 16;
  return (unsigned short)u;
}
static __device__ __forceinline__ float bf2f(unsigned short u) {
  return __uint_as_float(((unsigned)u) << 16);
}
// exact identity tanh(x) = 1 - 2/(exp(2x)+1)
static __device__ __forceinline__ float fast_tanh(float x) {
  return 1.f - 2.f / (__expf(2.f * x) + 1.f);
}

// async global(16B/lane) -> LDS, wave-uniform LDS base, per-lane global addr
static __device__ __forceinline__ void gload16(const unsigned short* g, char* l) {
  __builtin_amdgcn_global_load_lds(
      (const __attribute__((address_space(1))) unsigned int*)g,
      (__attribute__((address_space(3))) unsigned int*)l, 16, 0, 0);
}

// ---------------- K_prep_all: enc->bf16 (blocks 0..2047), W->bf16 (2048..3071), U_h (3072..3327) ----------------
__global__ void k_prep_all(const float* __restrict__ E, unsigned short* __restrict__ Eb,
                           const float* __restrict__ W, unsigned short* __restrict__ Wb,
                           const float* __restrict__ dh, const float* __restrict__ Uw,
                           float* __restrict__ Uh) {
  const int bid = blockIdx.x;
  if (bid < 2048) {
    const int n8 = M_DIM * (H_DIM / 8);              // 4,194,304 chunks
    const int stride = 2048 * 256;
    for (int idx = bid * 256 + threadIdx.x; idx < n8; idx += stride) {
      const float4* gp = (const float4*)(E + (size_t)idx * 8);
      float4 lo = gp[0], hi = gp[1];
      bf16x8 w;
      w[0] = (short)f2bf(lo.x); w[1] = (short)f2bf(lo.y);
      w[2] = (short)f2bf(lo.z); w[3] = (short)f2bf(lo.w);
      w[4] = (short)f2bf(hi.x); w[5] = (short)f2bf(hi.y);
      w[6] = (short)f2bf(hi.z); w[7] = (short)f2bf(hi.w);
      *(bf16x8*)(Eb + (size_t)idx * 8) = w;
    }
  } else if (bid < 3072) {
    const int idx = (bid - 2048) * 256 + threadIdx.x;  // 0 .. 262143
    float4 v = ((const float4*)W)[idx];
    ushort4 o;
    o.x = f2bf(v.x); o.y = f2bf(v.y); o.z = f2bf(v.z); o.w = f2bf(v.w);
    ((ushort4*)Wb)[idx] = o;
  } else {
    const int wave = threadIdx.x >> 6;
    const int lane = threadIdx.x & 63;
    const int o = (bid - 3072) * 4 + wave;             // 0..1023
    float uw[16];
#pragma unroll
    for (int k = 0; k < 16; ++k) uw[k] = Uw[o * H_DIM + k * 64 + lane];
    for (int b = 0; b < B_DIM; ++b) {
      float acc = 0.f;
#pragma unroll
      for (int k = 0; k < 16; ++k) acc += uw[k] * dh[b * H_DIM + k * 64 + lane];
#pragma unroll
      for (int msk = 32; msk >= 1; msk >>= 1) acc += __shfl_xor(acc, msk, 64);
      if (lane == 0) Uh[b * H_DIM + o] = acc;
    }
  }
}

// ---------------- K2: 256x256 counted-vmcnt fused att GEMM ----------------
// BM=256, BN=256, BK=64. 512 threads = 8 waves (2M x 4N), per-wave 128x64 tile
// (8x4 blocking of 16x16x32 frags). LDS: 2 buffers x (A 32KB + B 32KB) = 128KB.
#define A5_BM 256
#define A5_BN 256
#define A5_BUF 65536
#define NT_FAST 4      // n_tiles

__launch_bounds__(512, 2)
__global__ void k_att5(const unsigned short* __restrict__ Eb,
                       const unsigned short* __restrict__ Wb,
                       const float* __restrict__ Uh,
                       const float* __restrict__ vw,
                       float* __restrict__ att_p) {
  __shared__ __align__(16) char lds[2 * A5_BUF];   // 128 KB

  // XCD-friendly: blocks with same (bid&7) sit on one XCD
  const int bid = blockIdx.x;            // 0..511
  const int xj = bid & 7;
  const int q  = bid >> 3;               // 0..63
  const int n_tile = q & 3;              // 0..3
  const int m_tile = ((q >> 2) << 3) | xj;   // 0..127, bijective
  const int m0 = m_tile * A5_BM;
  const int n0 = n_tile * A5_BN;
  const int b  = m0 >> 10;               // 256 | 1024 -> single batch per tile

  const int tid  = threadIdx.x;          // 0..511
  const int wid  = tid >> 6;             // 0..7
  const int lane = tid & 63;
  const int wm = (wid >> 2) * 128;       // 0 / 128 (per-wave 128 rows)
  const int wn = (wid & 3) * 64;         // 0,64,128,192 (per-wave 64 cols)

  // Staging maps (linear LDS dest; inverse-swizzled global source; swizzled reads)
  size_t offA[4], offB[4];
  int ldsA[4], ldsB[4];
#pragma unroll
  for (int j = 0; j < 4; ++j) {
    const int chunk = j * 512 + tid;     // 0..2047 -> rows 0..255
    const int r  = chunk >> 3;
    const int c8 = (chunk & 7) ^ (r & 7);
    offA[j] = (size_t)(m0 + r) * H_DIM + c8 * 8;
    offB[j] = (size_t)(n0 + r) * H_DIM + c8 * 8;
    ldsA[j] = j * 8192 + wid * 1024;                 // A: [0, 32KB)
    ldsB[j] = 32768 + j * 8192 + wid * 1024;         // B: [32KB, 64KB)
  }

  auto stage = [&](int t) {              // 8 loads -> buf (t&1)
    char* dst = lds + (t & 1) * A5_BUF;
    const size_t k0 = (size_t)t * 64;
#pragma unroll
    for (int j = 0; j < 4; ++j) gload16(Eb + offA[j] + k0, dst + ldsA[j]);
#pragma unroll
    for (int j = 0; j < 4; ++j) gload16(Wb + offB[j] + k0, dst + ldsB[j]);
  };

  const int fr_row = lane & 15;
  const int fr_k8  = lane >> 4;

  f32x4 acc[8][4];
#pragma unroll
  for (int mf = 0; mf < 8; ++mf)
#pragma unroll
    for (int nf = 0; nf < 4; ++nf) acc[mf][nf] = (f32x4)(0.0f);

  stage(0);                              // 8 loads in flight

  for (int t = 0; t < 16; ++t) {
    // Ledger: after stage(t+1), outstanding <= 16 (t+1's 8 + t's remainder);
    // vmcnt(8) -> tile t fully landed, t+1 stays in flight. Tail drains to 0.
    if (t < 15) {
      stage(t + 1);
      asm volatile("s_waitcnt vmcnt(8)" ::: "memory");
    } else {
      asm volatile("s_waitcnt vmcnt(0)" ::: "memory");
    }
    __builtin_amdgcn_s_barrier();        // other waves' DMA for tile t visible

    const char* As = lds + (t & 1) * A5_BUF;
    const char* Bs = As + 32768;
#pragma unroll
    for (int kh = 0; kh < 2; ++kh) {
      const int kb = kh * 32 + fr_k8 * 8;
      bf16x8 af[8], bfr[4];
#pragma unroll
      for (int mf = 0; mf < 8; ++mf) {
        const int row = wm + mf * 16 + fr_row;               // 0..255
        const int addr = (row * 128 + kb * 2) ^ ((row & 7) << 4);
        af[mf] = *(const bf16x8*)(As + addr);
      }
#pragma unroll
      for (int nf = 0; nf < 4; ++nf) {
        const int row = wn + nf * 16 + fr_row;               // 0..255
        const int addr = (row * 128 + kb * 2) ^ ((row & 7) << 4);
        bfr[nf] = *(const bf16x8*)(Bs + addr);
      }
      __builtin_amdgcn_s_barrier();      // align wave roles; lgkm by compiler
      __builtin_amdgcn_s_setprio(1);
#pragma unroll
      for (int mf = 0; mf < 8; ++mf)
#pragma unroll
        for (int nf = 0; nf < 4; ++nf)
          acc[mf][nf] = __builtin_amdgcn_mfma_f32_16x16x32_bf16(af[mf], bfr[nf], acc[mf][nf], 0, 0, 0);
      __builtin_amdgcn_s_setprio(0);
      __builtin_amdgcn_s_barrier();
    }
  }

  float* red = (float*)lds;   // [8 waves][128 rows]

  // Epilogue: tanh(acc + Uh)*v, reduce over this wave's 64 o's.
  // D frag: col = lane&15 (n), row = (lane>>4)*4 + reg (m)
  const int col = lane & 15;
  const int rhi = lane >> 4;
  float uh[4], vv[4];
#pragma unroll
  for (int nf = 0; nf < 4; ++nf) {
    const int o = n0 + wn + nf * 16 + col;
    uh[nf] = Uh[b * H_DIM + o];
    vv[nf] = vw[o];
  }
#pragma unroll
  for (int mf = 0; mf < 8; ++mf) {
    float rs[4];
#pragma unroll
    for (int jj = 0; jj < 4; ++jj) {
      float s = 0.f;
#pragma unroll
      for (int nf = 0; nf < 4; ++nf) {
        const float x = acc[mf][nf][jj] + uh[nf];
        s += fast_tanh(x) * vv[nf];
      }
      rs[jj] = s;
    }
#pragma unroll
    for (int msk = 1; msk < 16; msk <<= 1) {
#pragma unroll
      for (int jj = 0; jj < 4; ++jj) rs[jj] += __shfl_xor(rs[jj], msk, 64);
    }
    if (col == 0) {
#pragma unroll
      for (int jj = 0; jj < 4; ++jj) {
        const int local = mf * 16 + rhi * 4 + jj;   // row within wave's 128
        red[wid * 128 + local] = rs[jj];
      }
    }
  }
  __syncthreads();
  if (tid < 256) {
    const int mhalf = tid >> 7;          // waves {0..3} own rows 0..127, {4..7} own 128..255
    const int loc = tid & 127;
    float sum = 0.f;
#pragma unroll
    for (int j = 0; j < 4; ++j) sum += red[(mhalf * 4 + j) * 128 + loc];
    att_p[(size_t)n_tile * M_DIM + m0 + tid] = sum;
  }
}

// ---------------- K3: fused softmax + context partials ----------------
// 128 blocks = b(32) x sq(4). Each block recomputes row-b softmax locally,
// sq==0 writes alpha, all compute ctx partials.
__global__ void k_ctx_sm(const unsigned short* __restrict__ Eb,
                         const float* __restrict__ att_p,
                         float* __restrict__ alpha_out,
                         float* __restrict__ ctx_p) {
  const int bid = blockIdx.x;
  const int b  = bid >> 2;
  const int sq = bid & 3;
  const int tid = threadIdx.x;
  __shared__ float red[8];
  __shared__ float qa[256];

  float a[4];
  float mx = -1e30f;
#pragma unroll
  for (int i = 0; i < 4; ++i) {
    const int s = i * 256 + tid;
    float v = 0.f;
#pragma unroll
    for (int t = 0; t < NT_FAST; ++t) v += att_p[(size_t)t * M_DIM + b * S_DIM + s];
    a[i] = v;
    mx = fmaxf(mx, v);
  }
#pragma unroll
  for (int msk = 32; msk >= 1; msk >>= 1) mx = fmaxf(mx, __shfl_xor(mx, msk, 64));
  if ((tid & 63) == 0) red[tid >> 6] = mx;
  __syncthreads();
  mx = fmaxf(fmaxf(red[0], red[1]), fmaxf(red[2], red[3]));
  float sum = 0.f;
#pragma unroll
  for (int i = 0; i < 4; ++i) { a[i] = __expf(a[i] - mx); sum += a[i]; }
#pragma unroll
  for (int msk = 32; msk >= 1; msk >>= 1) sum += __shfl_xor(sum, msk, 64);
  if ((tid & 63) == 0) red[4 + (tid >> 6)] = sum;
  __syncthreads();
  const float inv = 1.f / (red[4] + red[5] + red[6] + red[7]);
  if (sq == 0) {
#pragma unroll
    for (int i = 0; i < 4; ++i) alpha_out[b * S_DIM + i * 256 + tid] = a[i] * inv;
  }
  qa[tid] = a[sq] * inv;                  // alpha for s = sq*256 + tid
  __syncthreads();

  const int h = tid * 4;                  // 0..1020
  const unsigned short* ep = Eb + (size_t)b * S_DIM * H_DIM + (size_t)(sq * 256) * H_DIM + h;
  float4 acc = make_float4(0.f, 0.f, 0.f, 0.f);
  for (int s = 0; s < 256; ++s) {
    const float al = qa[s];
    ushort4 v = *(const ushort4*)(ep + (size_t)s * H_DIM);
    acc.x += al * bf2f(v.x);
    acc.y += al * bf2f(v.y);
    acc.z += al * bf2f(v.z);
    acc.w += al * bf2f(v.w);
  }
  *(float4*)&ctx_p[(size_t)sq * (B_DIM * H_DIM) + b * H_DIM + h] = acc;
}

// ---------------- K5: reduce context partials -> d_out ----------------
__global__ void k_ctx_reduce(const float* __restrict__ ctx_p, float* __restrict__ ctx) {
  const int i = blockIdx.x * 256 + threadIdx.x;
  ctx[i] = ctx_p[i] + ctx_p[32768 + i] + ctx_p[65536 + i] + ctx_p[98304 + i];
}

extern "C" void kernel_launch(void* const* d_in, const int* in_sizes, int n_in,
                              void* d_out, int out_size, void* d_ws, size_t ws_size,
                              hipStream_t stream) {
  (void)in_sizes; (void)n_in; (void)out_size; (void)ws_size;
  const float* dh  = (const float*)d_in[0];
  const float* enc = (const float*)d_in[1];
  const float* Uw  = (const float*)d_in[2];
  const float* Ww  = (const float*)d_in[3];
  const float* vw  = (const float*)d_in[4];
  float* ctx_out = (float*)d_out;                 // [32,1024]
  float* alpha   = (float*)d_out + M_DIM;         // [32,1024]

  char* ws = (char*)d_ws;
  const size_t EB_BYTES = (size_t)M_DIM * H_DIM * 2;            // 64 MiB

  unsigned short* Eb = (unsigned short*)ws;
  unsigned short* Wb = (unsigned short*)(ws + EB_BYTES);
  float* Uh    = (float*)(ws + EB_BYTES + (2u << 20));
  float* att_p = (float*)(ws + EB_BYTES + (2u << 20) + (128u << 10));
  float* ctx_p = (float*)(ws + EB_BYTES + (2u << 20) + (128u << 10) + (1u << 20));

  k_prep_all<<<3328, 256, 0, stream>>>(enc, Eb, Ww, Wb, dh, Uw, Uh);
  k_att5<<<512, 512, 0, stream>>>(Eb, Wb, Uh, vw, att_p);
  k_ctx_sm<<<128, 256, 0, stream>>>(Eb, att_p, alpha, ctx_p);
  k_ctx_reduce<<<128, 256, 0, stream>>>(ctx_p, ctx_out);
}

// Round 8
// 139.787 us; speedup vs baseline: 1.3204x; 1.0633x over previous
//
#include <hip/hip_runtime.h>
#include <hip/hip_bf16.h>
#include <cstdint>
#include <cstddef>

#define B_DIM 32
#define S_DIM 1024
#define H_DIM 1024
#define M_DIM (B_DIM * S_DIM)   // 32768

typedef __attribute__((ext_vector_type(8))) short bf16x8;
typedef __attribute__((ext_vector_type(4))) float f32x4;

// round-to-nearest-even fp32 -> bf16 (bit trick; no NaN inputs here)
static __device__ __forceinline__ unsigned short f2bf(float f) {
  unsigned u = __float_as_uint(f);
  u = (u + 0x7FFFu + ((u >> 16) & 1u)) >> 16;
  return (unsigned short)u;
}
static __device__ __forceinline__ float bf2f(unsigned short u) {
  return __uint_as_float(((unsigned)u) << 16);
}
// exact identity tanh(x) = 1 - 2/(exp(2x)+1)
static __device__ __forceinline__ float fast_tanh(float x) {
  return 1.f - 2.f / (__expf(2.f * x) + 1.f);
}

// async global(16B/lane) -> LDS, wave-uniform LDS base, per-lane global addr
static __device__ __forceinline__ void gload16(const unsigned short* g, char* l) {
  __builtin_amdgcn_global_load_lds(
      (const __attribute__((address_space(1))) unsigned int*)g,
      (__attribute__((address_space(3))) unsigned int*)l, 16, 0, 0);
}

// ---------------- K_prep_all: enc->bf16 (blocks 0..2047), W->bf16 (2048..3071), U_h (3072..3327) ----------------
__global__ void k_prep_all(const float* __restrict__ E, unsigned short* __restrict__ Eb,
                           const float* __restrict__ W, unsigned short* __restrict__ Wb,
                           const float* __restrict__ dh, const float* __restrict__ Uw,
                           float* __restrict__ Uh) {
  const int bid = blockIdx.x;
  if (bid < 2048) {
    const int n8 = M_DIM * (H_DIM / 8);              // 4,194,304 chunks
    const int stride = 2048 * 256;
    for (int idx = bid * 256 + threadIdx.x; idx < n8; idx += stride) {
      const float4* gp = (const float4*)(E + (size_t)idx * 8);
      float4 lo = gp[0], hi = gp[1];
      bf16x8 w;
      w[0] = (short)f2bf(lo.x); w[1] = (short)f2bf(lo.y);
      w[2] = (short)f2bf(lo.z); w[3] = (short)f2bf(lo.w);
      w[4] = (short)f2bf(hi.x); w[5] = (short)f2bf(hi.y);
      w[6] = (short)f2bf(hi.z); w[7] = (short)f2bf(hi.w);
      *(bf16x8*)(Eb + (size_t)idx * 8) = w;
    }
  } else if (bid < 3072) {
    const int idx = (bid - 2048) * 256 + threadIdx.x;  // 0 .. 262143
    float4 v = ((const float4*)W)[idx];
    ushort4 o;
    o.x = f2bf(v.x); o.y = f2bf(v.y); o.z = f2bf(v.z); o.w = f2bf(v.w);
    ((ushort4*)Wb)[idx] = o;
  } else {
    const int wave = threadIdx.x >> 6;
    const int lane = threadIdx.x & 63;
    const int o = (bid - 3072) * 4 + wave;             // 0..1023
    float uw[16];
#pragma unroll
    for (int k = 0; k < 16; ++k) uw[k] = Uw[o * H_DIM + k * 64 + lane];
    for (int b = 0; b < B_DIM; ++b) {
      float acc = 0.f;
#pragma unroll
      for (int k = 0; k < 16; ++k) acc += uw[k] * dh[b * H_DIM + k * 64 + lane];
#pragma unroll
      for (int msk = 32; msk >= 1; msk >>= 1) acc += __shfl_xor(acc, msk, 64);
      if (lane == 0) Uh[b * H_DIM + o] = acc;
    }
  }
}

// ---------------- K2: 256x256 single-barrier-per-tile fused att GEMM ----------------
// BM=256, BN=256, BK=64. 512 threads = 8 waves (2M x 4N), per-wave 128x64 tile
// (8x4 blocking of 16x16x32 frags). LDS: 2 buffers x (A 32KB + B 32KB) = 128KB.
#define A5_BM 256
#define A5_BN 256
#define A5_BUF 65536
#define NT_FAST 4      // n_tiles

__launch_bounds__(512, 2)
__global__ void k_att6(const unsigned short* __restrict__ Eb,
                       const unsigned short* __restrict__ Wb,
                       const float* __restrict__ Uh,
                       const float* __restrict__ vw,
                       float* __restrict__ att_p) {
  __shared__ __align__(16) char lds[2 * A5_BUF];   // 128 KB

  // XCD-friendly: blocks with same (bid&7) sit on one XCD
  const int bid = blockIdx.x;            // 0..511
  const int xj = bid & 7;
  const int q  = bid >> 3;               // 0..63
  const int n_tile = q & 3;              // 0..3
  const int m_tile = ((q >> 2) << 3) | xj;   // 0..127, bijective
  const int m0 = m_tile * A5_BM;
  const int n0 = n_tile * A5_BN;
  const int b  = m0 >> 10;

  const int tid  = threadIdx.x;          // 0..511
  const int wid  = tid >> 6;             // 0..7
  const int lane = tid & 63;
  const int wm = (wid >> 2) * 128;       // 0 / 128 (per-wave 128 rows)
  const int wn = (wid & 3) * 64;         // 0,64,128,192 (per-wave 64 cols)

  // Staging maps (linear LDS dest; inverse-swizzled global source; swizzled reads)
  size_t offA[4], offB[4];
  int ldsA[4], ldsB[4];
#pragma unroll
  for (int j = 0; j < 4; ++j) {
    const int chunk = j * 512 + tid;     // 0..2047 -> rows 0..255
    const int r  = chunk >> 3;
    const int c8 = (chunk & 7) ^ (r & 7);
    offA[j] = (size_t)(m0 + r) * H_DIM + c8 * 8;
    offB[j] = (size_t)(n0 + r) * H_DIM + c8 * 8;
    ldsA[j] = j * 8192 + wid * 1024;                 // A: [0, 32KB)
    ldsB[j] = 32768 + j * 8192 + wid * 1024;         // B: [32KB, 64KB)
  }

  auto stage = [&](int t) {              // 8 DMA loads -> buf (t&1)
    char* dst = lds + (t & 1) * A5_BUF;
    const size_t k0 = (size_t)t * 64;
#pragma unroll
    for (int j = 0; j < 4; ++j) gload16(Eb + offA[j] + k0, dst + ldsA[j]);
#pragma unroll
    for (int j = 0; j < 4; ++j) gload16(Wb + offB[j] + k0, dst + ldsB[j]);
  };

  const int fr_row = lane & 15;
  const int fr_k8  = lane >> 4;

  f32x4 acc[8][4];
#pragma unroll
  for (int mf = 0; mf < 8; ++mf)
#pragma unroll
    for (int nf = 0; nf < 4; ++nf) acc[mf][nf] = (f32x4)(0.0f);

  stage(0);                              // 8 loads in flight

  for (int t = 0; t < 16; ++t) {
    // Own DMAs for tile t landed; barrier makes all waves' DMAs visible.
    // Issue->wait distance is a full K-tile (~3000 cy) so this drain is ~free.
    asm volatile("s_waitcnt vmcnt(0)" ::: "memory");
    __builtin_amdgcn_s_barrier();
    asm volatile("" ::: "memory");       // keep ds_reads below the barrier

    // Safe: buf[(t+1)&1] was last READ in iter t-1; every wave passed this
    // barrier => finished iter t-1 entirely.
    if (t < 15) stage(t + 1);

    const char* As = lds + (t & 1) * A5_BUF;
    const char* Bs = As + 32768;

    // Both kh frag sets are separate SSA values -> compiler interleaves the
    // kh=1 ds_reads (and the DMA issue) under the kh=0 MFMA cluster with
    // fine-grained lgkmcnt. No barrier between reads and MFMA.
#pragma unroll
    for (int kh = 0; kh < 2; ++kh) {
      const int kb = kh * 32 + fr_k8 * 8;
      bf16x8 af[8], bfr[4];
#pragma unroll
      for (int mf = 0; mf < 8; ++mf) {
        const int row = wm + mf * 16 + fr_row;               // 0..255
        const int addr = (row * 128 + kb * 2) ^ ((row & 7) << 4);
        af[mf] = *(const bf16x8*)(As + addr);
      }
#pragma unroll
      for (int nf = 0; nf < 4; ++nf) {
        const int row = wn + nf * 16 + fr_row;               // 0..255
        const int addr = (row * 128 + kb * 2) ^ ((row & 7) << 4);
        bfr[nf] = *(const bf16x8*)(Bs + addr);
      }
      __builtin_amdgcn_s_setprio(1);
#pragma unroll
      for (int mf = 0; mf < 8; ++mf)
#pragma unroll
        for (int nf = 0; nf < 4; ++nf)
          acc[mf][nf] = __builtin_amdgcn_mfma_f32_16x16x32_bf16(af[mf], bfr[nf], acc[mf][nf], 0, 0, 0);
      __builtin_amdgcn_s_setprio(0);
    }
  }

  float* red = (float*)lds;   // [8 waves][128 rows]; buf0 rows safe (see ledger)

  // Epilogue: tanh(acc + Uh)*v, reduce over this wave's 64 o's.
  // D frag: col = lane&15 (n), row = (lane>>4)*4 + reg (m)
  const int col = lane & 15;
  const int rhi = lane >> 4;
  float uh[4], vv[4];
#pragma unroll
  for (int nf = 0; nf < 4; ++nf) {
    const int o = n0 + wn + nf * 16 + col;
    uh[nf] = Uh[b * H_DIM + o];
    vv[nf] = vw[o];
  }
#pragma unroll
  for (int mf = 0; mf < 8; ++mf) {
    float rs[4];
#pragma unroll
    for (int jj = 0; jj < 4; ++jj) {
      float s = 0.f;
#pragma unroll
      for (int nf = 0; nf < 4; ++nf) {
        const float x = acc[mf][nf][jj] + uh[nf];
        s += fast_tanh(x) * vv[nf];
      }
      rs[jj] = s;
    }
#pragma unroll
    for (int msk = 1; msk < 16; msk <<= 1) {
#pragma unroll
      for (int jj = 0; jj < 4; ++jj) rs[jj] += __shfl_xor(rs[jj], msk, 64);
    }
    if (col == 0) {
#pragma unroll
      for (int jj = 0; jj < 4; ++jj) {
        const int local = mf * 16 + rhi * 4 + jj;   // row within wave's 128
        red[wid * 128 + local] = rs[jj];
      }
    }
  }
  __syncthreads();
  if (tid < 256) {
    const int mhalf = tid >> 7;          // waves {0..3} own rows 0..127, {4..7} own 128..255
    const int loc = tid & 127;
    float sum = 0.f;
#pragma unroll
    for (int j = 0; j < 4; ++j) sum += red[(mhalf * 4 + j) * 128 + loc];
    att_p[(size_t)n_tile * M_DIM + m0 + tid] = sum;
  }
}

// ---------------- K3: fused softmax + context partials ----------------
// 128 blocks = b(32) x sq(4). Each block recomputes row-b softmax locally,
// sq==0 writes alpha, all compute ctx partials.
__global__ void k_ctx_sm(const unsigned short* __restrict__ Eb,
                         const float* __restrict__ att_p,
                         float* __restrict__ alpha_out,
                         float* __restrict__ ctx_p) {
  const int bid = blockIdx.x;
  const int b  = bid >> 2;
  const int sq = bid & 3;
  const int tid = threadIdx.x;
  __shared__ float red[8];
  __shared__ float qa[256];

  float a[4];
  float mx = -1e30f;
#pragma unroll
  for (int i = 0; i < 4; ++i) {
    const int s = i * 256 + tid;
    float v = 0.f;
#pragma unroll
    for (int t = 0; t < NT_FAST; ++t) v += att_p[(size_t)t * M_DIM + b * S_DIM + s];
    a[i] = v;
    mx = fmaxf(mx, v);
  }
#pragma unroll
  for (int msk = 32; msk >= 1; msk >>= 1) mx = fmaxf(mx, __shfl_xor(mx, msk, 64));
  if ((tid & 63) == 0) red[tid >> 6] = mx;
  __syncthreads();
  mx = fmaxf(fmaxf(red[0], red[1]), fmaxf(red[2], red[3]));
  float sum = 0.f;
#pragma unroll
  for (int i = 0; i < 4; ++i) { a[i] = __expf(a[i] - mx); sum += a[i]; }
#pragma unroll
  for (int msk = 32; msk >= 1; msk >>= 1) sum += __shfl_xor(sum, msk, 64);
  if ((tid & 63) == 0) red[4 + (tid >> 6)] = sum;
  __syncthreads();
  const float inv = 1.f / (red[4] + red[5] + red[6] + red[7]);
  if (sq == 0) {
#pragma unroll
    for (int i = 0; i < 4; ++i) alpha_out[b * S_DIM + i * 256 + tid] = a[i] * inv;
  }
  qa[tid] = a[sq] * inv;                  // alpha for s = sq*256 + tid
  __syncthreads();

  const int h = tid * 4;                  // 0..1020
  const unsigned short* ep = Eb + (size_t)b * S_DIM * H_DIM + (size_t)(sq * 256) * H_DIM + h;
  float4 acc = make_float4(0.f, 0.f, 0.f, 0.f);
  for (int s = 0; s < 256; ++s) {
    const float al = qa[s];
    ushort4 v = *(const ushort4*)(ep + (size_t)s * H_DIM);
    acc.x += al * bf2f(v.x);
    acc.y += al * bf2f(v.y);
    acc.z += al * bf2f(v.z);
    acc.w += al * bf2f(v.w);
  }
  *(float4*)&ctx_p[(size_t)sq * (B_DIM * H_DIM) + b * H_DIM + h] = acc;
}

// ---------------- K5: reduce context partials -> d_out ----------------
__global__ void k_ctx_reduce(const float* __restrict__ ctx_p, float* __restrict__ ctx) {
  const int i = blockIdx.x * 256 + threadIdx.x;
  ctx[i] = ctx_p[i] + ctx_p[32768 + i] + ctx_p[65536 + i] + ctx_p[98304 + i];
}

extern "C" void kernel_launch(void* const* d_in, const int* in_sizes, int n_in,
                              void* d_out, int out_size, void* d_ws, size_t ws_size,
                              hipStream_t stream) {
  (void)in_sizes; (void)n_in; (void)out_size; (void)ws_size;
  const float* dh  = (const float*)d_in[0];
  const float* enc = (const float*)d_in[1];
  const float* Uw  = (const float*)d_in[2];
  const float* Ww  = (const float*)d_in[3];
  const float* vw  = (const float*)d_in[4];
  float* ctx_out = (float*)d_out;                 // [32,1024]
  float* alpha   = (float*)d_out + M_DIM;         // [32,1024]

  char* ws = (char*)d_ws;
  const size_t EB_BYTES = (size_t)M_DIM * H_DIM * 2;            // 64 MiB

  unsigned short* Eb = (unsigned short*)ws;
  unsigned short* Wb = (unsigned short*)(ws + EB_BYTES);
  float* Uh    = (float*)(ws + EB_BYTES + (2u << 20));
  float* att_p = (float*)(ws + EB_BYTES + (2u << 20) + (128u << 10));
  float* ctx_p = (float*)(ws + EB_BYTES + (2u << 20) + (128u << 10) + (1u << 20));

  k_prep_all<<<3328, 256, 0, stream>>>(enc, Eb, Ww, Wb, dh, Uw, Uh);
  k_att6<<<512, 512, 0, stream>>>(Eb, Wb, Uh, vw, att_p);
  k_ctx_sm<<<128, 256, 0, stream>>>(Eb, att_p, alpha, ctx_p);
  k_ctx_reduce<<<128, 256, 0, stream>>>(ctx_p, ctx_out);
}

// Round 9
// 132.619 us; speedup vs baseline: 1.3918x; 1.0541x over previous
//
#include <hip/hip_runtime.h>
#include <hip/hip_bf16.h>
#include <cstdint>
#include <cstddef>

#define B_DIM 32
#define S_DIM 1024
#define H_DIM 1024
#define M_DIM (B_DIM * S_DIM)   // 32768

typedef __attribute__((ext_vector_type(8))) short bf16x8;
typedef __attribute__((ext_vector_type(4))) float f32x4;

// round-to-nearest-even fp32 -> bf16 (bit trick; no NaN inputs here)
static __device__ __forceinline__ unsigned short f2bf(float f) {
  unsigned u = __float_as_uint(f);
  u = (u + 0x7FFFu + ((u >> 16) & 1u)) >> 16;
  return (unsigned short)u;
}
static __device__ __forceinline__ float bf2f(unsigned short u) {
  return __uint_as_float(((unsigned)u) << 16);
}
// exact identity tanh(x) = 1 - 2/(exp(2x)+1)
static __device__ __forceinline__ float fast_tanh(float x) {
  return 1.f - 2.f / (__expf(2.f * x) + 1.f);
}

// async global(16B/lane) -> LDS, wave-uniform LDS base, per-lane global addr
static __device__ __forceinline__ void gload16(const unsigned short* g, char* l) {
  __builtin_amdgcn_global_load_lds(
      (const __attribute__((address_space(1))) unsigned int*)g,
      (__attribute__((address_space(3))) unsigned int*)l, 16, 0, 0);
}

// ---------------- K_prep_all ----------------
// Blocks 0..1023: U_h (o = bid, wave handles 8 b's) -- FIRST so the latency-bound
// part overlaps the convert instead of tailing it.
// Blocks 1024..2047: W -> bf16. Blocks 2048..4095: enc -> bf16 (grid-stride).
__global__ void k_prep_all(const float* __restrict__ E, unsigned short* __restrict__ Eb,
                           const float* __restrict__ W, unsigned short* __restrict__ Wb,
                           const float* __restrict__ dh, const float* __restrict__ Uw,
                           float* __restrict__ Uh) {
  const int bid = blockIdx.x;
  if (bid < 1024) {
    const int wave = threadIdx.x >> 6;
    const int lane = threadIdx.x & 63;
    const int o = bid;                                 // 0..1023
    float uw[16];
#pragma unroll
    for (int k = 0; k < 16; ++k) uw[k] = Uw[o * H_DIM + k * 64 + lane];
#pragma unroll
    for (int bb = 0; bb < 8; ++bb) {
      const int b = wave * 8 + bb;                     // 0..31
      float acc = 0.f;
#pragma unroll
      for (int k = 0; k < 16; ++k) acc += uw[k] * dh[b * H_DIM + k * 64 + lane];
#pragma unroll
      for (int msk = 32; msk >= 1; msk >>= 1) acc += __shfl_xor(acc, msk, 64);
      if (lane == 0) Uh[b * H_DIM + o] = acc;
    }
  } else if (bid < 2048) {
    const int idx = (bid - 1024) * 256 + threadIdx.x;  // 0 .. 262143
    float4 v = ((const float4*)W)[idx];
    ushort4 o;
    o.x = f2bf(v.x); o.y = f2bf(v.y); o.z = f2bf(v.z); o.w = f2bf(v.w);
    ((ushort4*)Wb)[idx] = o;
  } else {
    const int n8 = M_DIM * (H_DIM / 8);                // 4,194,304 chunks
    const int stride = 2048 * 256;
    for (int idx = (bid - 2048) * 256 + threadIdx.x; idx < n8; idx += stride) {
      const float4* gp = (const float4*)(E + (size_t)idx * 8);
      float4 lo = gp[0], hi = gp[1];
      bf16x8 w;
      w[0] = (short)f2bf(lo.x); w[1] = (short)f2bf(lo.y);
      w[2] = (short)f2bf(lo.z); w[3] = (short)f2bf(lo.w);
      w[4] = (short)f2bf(hi.x); w[5] = (short)f2bf(hi.y);
      w[6] = (short)f2bf(hi.z); w[7] = (short)f2bf(hi.w);
      *(bf16x8*)(Eb + (size_t)idx * 8) = w;
    }
  }
}

// ---------------- K2: 256x256 4-phase interleaved fused att GEMM ----------------
// BM=256, BN=256, BK=64. 512 threads = 8 waves (2M x 4N), per-wave 128x64 tile.
// LDS: 2 buffers x (A 32KB + B 32KB) = 128KB. Per K-tile: 4 phases x 16 MFMA.
#define A5_BM 256
#define A5_BN 256
#define A5_BUF 65536
#define NT_FAST 4      // n_tiles

#define LDFRAG(base, row, kh) \
  (*(const bf16x8*)((base) + ((((row) * 128) + ((kh) * 32 + fr_k8 * 8) * 2) ^ (((row) & 7) << 4))))

__launch_bounds__(512, 2)
__global__ void k_att7(const unsigned short* __restrict__ Eb,
                       const unsigned short* __restrict__ Wb,
                       const float* __restrict__ Uh,
                       const float* __restrict__ vw,
                       float* __restrict__ att_p) {
  __shared__ __align__(16) char lds[2 * A5_BUF];   // 128 KB

  // XCD-friendly: blocks with same (bid&7) sit on one XCD
  const int bid = blockIdx.x;            // 0..511
  const int xj = bid & 7;
  const int q  = bid >> 3;               // 0..63
  const int n_tile = q & 3;              // 0..3
  const int m_tile = ((q >> 2) << 3) | xj;   // 0..127, bijective
  const int m0 = m_tile * A5_BM;
  const int n0 = n_tile * A5_BN;
  const int b  = m0 >> 10;

  const int tid  = threadIdx.x;          // 0..511
  const int wid  = tid >> 6;             // 0..7
  const int lane = tid & 63;
  const int wm = (wid >> 2) * 128;       // 0 / 128
  const int wn = (wid & 3) * 64;         // 0,64,128,192

  // Staging maps (linear LDS dest; inverse-swizzled global source; swizzled reads)
  size_t offA[4], offB[4];
  int ldsA[4], ldsB[4];
#pragma unroll
  for (int j = 0; j < 4; ++j) {
    const int chunk = j * 512 + tid;     // 0..2047 -> rows 0..255
    const int r  = chunk >> 3;
    const int c8 = (chunk & 7) ^ (r & 7);
    offA[j] = (size_t)(m0 + r) * H_DIM + c8 * 8;
    offB[j] = (size_t)(n0 + r) * H_DIM + c8 * 8;
    ldsA[j] = j * 8192 + wid * 1024;                 // A: [0, 32KB)
    ldsB[j] = 32768 + j * 8192 + wid * 1024;         // B: [32KB, 64KB)
  }

  const int fr_row = lane & 15;
  const int fr_k8  = lane >> 4;

  f32x4 acc[8][4];
#pragma unroll
  for (int mf = 0; mf < 8; ++mf)
#pragma unroll
    for (int nf = 0; nf < 4; ++nf) acc[mf][nf] = (f32x4)(0.0f);

  {  // prologue: stage tile 0 fully
    char* dst = lds;
#pragma unroll
    for (int j = 0; j < 4; ++j) gload16(Eb + offA[j], dst + ldsA[j]);
#pragma unroll
    for (int j = 0; j < 4; ++j) gload16(Wb + offB[j], dst + ldsB[j]);
  }

  for (int t = 0; t < 16; ++t) {
    // Tile t's 8 DMAs were fully issued >= 4 phases ago -> drain is ~free.
    asm volatile("s_waitcnt vmcnt(0)" ::: "memory");
    __builtin_amdgcn_s_barrier();        // all waves' DMAs visible; t-1 reads done
    asm volatile("" ::: "memory");

    const char* As = lds + (t & 1) * A5_BUF;
    const char* Bs = As + 32768;
    char* dst = lds + ((t + 1) & 1) * A5_BUF;
    const size_t k1 = (size_t)(t + 1) * 64;
    const bool st = (t < 15);

    bf16x8 afl[8], afh[8], b01[4], b23[4], b01b[4];

    // ---- Phase 1: read af_lo(8) + bfr01(4); stage A0,A1; MFMA Q00 ----
#pragma unroll
    for (int mf = 0; mf < 4; ++mf) {
      afl[mf * 2 + 0] = LDFRAG(As, wm + mf * 16 + fr_row, 0);
      afl[mf * 2 + 1] = LDFRAG(As, wm + mf * 16 + fr_row, 1);
    }
#pragma unroll
    for (int nf = 0; nf < 2; ++nf) {
      b01[nf * 2 + 0] = LDFRAG(Bs, wn + nf * 16 + fr_row, 0);
      b01[nf * 2 + 1] = LDFRAG(Bs, wn + nf * 16 + fr_row, 1);
    }
    if (st) { gload16(Eb + offA[0] + k1, dst + ldsA[0]);
              gload16(Eb + offA[1] + k1, dst + ldsA[1]); }
    __builtin_amdgcn_s_barrier();
    asm volatile("s_waitcnt lgkmcnt(0)" ::: "memory");
    __builtin_amdgcn_sched_barrier(0);
    __builtin_amdgcn_s_setprio(1);
#pragma unroll
    for (int mf = 0; mf < 4; ++mf)
#pragma unroll
      for (int nf = 0; nf < 2; ++nf) {
        acc[mf][nf] = __builtin_amdgcn_mfma_f32_16x16x32_bf16(afl[mf*2+0], b01[nf*2+0], acc[mf][nf], 0, 0, 0);
        acc[mf][nf] = __builtin_amdgcn_mfma_f32_16x16x32_bf16(afl[mf*2+1], b01[nf*2+1], acc[mf][nf], 0, 0, 0);
      }
    __builtin_amdgcn_s_setprio(0);
    __builtin_amdgcn_s_barrier();

    // ---- Phase 2: read bfr23(4); stage A2,A3; MFMA Q01 ----
#pragma unroll
    for (int nf = 0; nf < 2; ++nf) {
      b23[nf * 2 + 0] = LDFRAG(Bs, wn + (nf + 2) * 16 + fr_row, 0);
      b23[nf * 2 + 1] = LDFRAG(Bs, wn + (nf + 2) * 16 + fr_row, 1);
    }
    if (st) { gload16(Eb + offA[2] + k1, dst + ldsA[2]);
              gload16(Eb + offA[3] + k1, dst + ldsA[3]); }
    __builtin_amdgcn_s_barrier();
    asm volatile("s_waitcnt lgkmcnt(0)" ::: "memory");
    __builtin_amdgcn_sched_barrier(0);
    __builtin_amdgcn_s_setprio(1);
#pragma unroll
    for (int mf = 0; mf < 4; ++mf)
#pragma unroll
      for (int nf = 0; nf < 2; ++nf) {
        acc[mf][nf+2] = __builtin_amdgcn_mfma_f32_16x16x32_bf16(afl[mf*2+0], b23[nf*2+0], acc[mf][nf+2], 0, 0, 0);
        acc[mf][nf+2] = __builtin_amdgcn_mfma_f32_16x16x32_bf16(afl[mf*2+1], b23[nf*2+1], acc[mf][nf+2], 0, 0, 0);
      }
    __builtin_amdgcn_s_setprio(0);
    __builtin_amdgcn_s_barrier();

    // ---- Phase 3: read af_hi(8); stage B0,B1; MFMA Q11 ----
#pragma unroll
    for (int mf = 0; mf < 4; ++mf) {
      afh[mf * 2 + 0] = LDFRAG(As, wm + (mf + 4) * 16 + fr_row, 0);
      afh[mf * 2 + 1] = LDFRAG(As, wm + (mf + 4) * 16 + fr_row, 1);
    }
    if (st) { gload16(Wb + offB[0] + k1, dst + ldsB[0]);
              gload16(Wb + offB[1] + k1, dst + ldsB[1]); }
    __builtin_amdgcn_s_barrier();
    asm volatile("s_waitcnt lgkmcnt(0)" ::: "memory");
    __builtin_amdgcn_sched_barrier(0);
    __builtin_amdgcn_s_setprio(1);
#pragma unroll
    for (int mf = 0; mf < 4; ++mf)
#pragma unroll
      for (int nf = 0; nf < 2; ++nf) {
        acc[mf+4][nf+2] = __builtin_amdgcn_mfma_f32_16x16x32_bf16(afh[mf*2+0], b23[nf*2+0], acc[mf+4][nf+2], 0, 0, 0);
        acc[mf+4][nf+2] = __builtin_amdgcn_mfma_f32_16x16x32_bf16(afh[mf*2+1], b23[nf*2+1], acc[mf+4][nf+2], 0, 0, 0);
      }
    __builtin_amdgcn_s_setprio(0);
    __builtin_amdgcn_s_barrier();

    // ---- Phase 4: reload bfr01(4); stage B2,B3; MFMA Q10 ----
#pragma unroll
    for (int nf = 0; nf < 2; ++nf) {
      b01b[nf * 2 + 0] = LDFRAG(Bs, wn + nf * 16 + fr_row, 0);
      b01b[nf * 2 + 1] = LDFRAG(Bs, wn + nf * 16 + fr_row, 1);
    }
    if (st) { gload16(Wb + offB[2] + k1, dst + ldsB[2]);
              gload16(Wb + offB[3] + k1, dst + ldsB[3]); }
    __builtin_amdgcn_s_barrier();
    asm volatile("s_waitcnt lgkmcnt(0)" ::: "memory");
    __builtin_amdgcn_sched_barrier(0);
    __builtin_amdgcn_s_setprio(1);
#pragma unroll
    for (int mf = 0; mf < 4; ++mf)
#pragma unroll
      for (int nf = 0; nf < 2; ++nf) {
        acc[mf+4][nf] = __builtin_amdgcn_mfma_f32_16x16x32_bf16(afh[mf*2+0], b01b[nf*2+0], acc[mf+4][nf], 0, 0, 0);
        acc[mf+4][nf] = __builtin_amdgcn_mfma_f32_16x16x32_bf16(afh[mf*2+1], b01b[nf*2+1], acc[mf+4][nf], 0, 0, 0);
      }
    __builtin_amdgcn_s_setprio(0);
    __builtin_amdgcn_s_barrier();
  }

  float* red = (float*)lds;   // [8 waves][128 rows]

  // Epilogue: tanh(acc + Uh)*v, reduce over this wave's 64 o's.
  // D frag: col = lane&15 (n), row = (lane>>4)*4 + reg (m)
  const int col = lane & 15;
  const int rhi = lane >> 4;
  float uh[4], vv[4];
#pragma unroll
  for (int nf = 0; nf < 4; ++nf) {
    const int o = n0 + wn + nf * 16 + col;
    uh[nf] = Uh[b * H_DIM + o];
    vv[nf] = vw[o];
  }
#pragma unroll
  for (int mf = 0; mf < 8; ++mf) {
    float rs[4];
#pragma unroll
    for (int jj = 0; jj < 4; ++jj) {
      float s = 0.f;
#pragma unroll
      for (int nf = 0; nf < 4; ++nf) {
        const float x = acc[mf][nf][jj] + uh[nf];
        s += fast_tanh(x) * vv[nf];
      }
      rs[jj] = s;
    }
#pragma unroll
    for (int msk = 1; msk < 16; msk <<= 1) {
#pragma unroll
      for (int jj = 0; jj < 4; ++jj) rs[jj] += __shfl_xor(rs[jj], msk, 64);
    }
    if (col == 0) {
#pragma unroll
      for (int jj = 0; jj < 4; ++jj) {
        const int local = mf * 16 + rhi * 4 + jj;   // row within wave's 128
        red[wid * 128 + local] = rs[jj];
      }
    }
  }
  __syncthreads();
  if (tid < 256) {
    const int mhalf = tid >> 7;
    const int loc = tid & 127;
    float sum = 0.f;
#pragma unroll
    for (int j = 0; j < 4; ++j) sum += red[(mhalf * 4 + j) * 128 + loc];
    att_p[(size_t)n_tile * M_DIM + m0 + tid] = sum;
  }
}

// ---------------- K3: fused softmax + context partials ----------------
__global__ void k_ctx_sm(const unsigned short* __restrict__ Eb,
                         const float* __restrict__ att_p,
                         float* __restrict__ alpha_out,
                         float* __restrict__ ctx_p) {
  const int bid = blockIdx.x;
  const int b  = bid >> 2;
  const int sq = bid & 3;
  const int tid = threadIdx.x;
  __shared__ float red[8];
  __shared__ float qa[256];

  float a[4];
  float mx = -1e30f;
#pragma unroll
  for (int i = 0; i < 4; ++i) {
    const int s = i * 256 + tid;
    float v = 0.f;
#pragma unroll
    for (int t = 0; t < NT_FAST; ++t) v += att_p[(size_t)t * M_DIM + b * S_DIM + s];
    a[i] = v;
    mx = fmaxf(mx, v);
  }
#pragma unroll
  for (int msk = 32; msk >= 1; msk >>= 1) mx = fmaxf(mx, __shfl_xor(mx, msk, 64));
  if ((tid & 63) == 0) red[tid >> 6] = mx;
  __syncthreads();
  mx = fmaxf(fmaxf(red[0], red[1]), fmaxf(red[2], red[3]));
  float sum = 0.f;
#pragma unroll
  for (int i = 0; i < 4; ++i) { a[i] = __expf(a[i] - mx); sum += a[i]; }
#pragma unroll
  for (int msk = 32; msk >= 1; msk >>= 1) sum += __shfl_xor(sum, msk, 64);
  if ((tid & 63) == 0) red[4 + (tid >> 6)] = sum;
  __syncthreads();
  const float inv = 1.f / (red[4] + red[5] + red[6] + red[7]);
  if (sq == 0) {
#pragma unroll
    for (int i = 0; i < 4; ++i) alpha_out[b * S_DIM + i * 256 + tid] = a[i] * inv;
  }
  qa[tid] = a[sq] * inv;
  __syncthreads();

  const int h = tid * 4;
  const unsigned short* ep = Eb + (size_t)b * S_DIM * H_DIM + (size_t)(sq * 256) * H_DIM + h;
  float4 acc = make_float4(0.f, 0.f, 0.f, 0.f);
  for (int s = 0; s < 256; ++s) {
    const float al = qa[s];
    ushort4 v = *(const ushort4*)(ep + (size_t)s * H_DIM);
    acc.x += al * bf2f(v.x);
    acc.y += al * bf2f(v.y);
    acc.z += al * bf2f(v.z);
    acc.w += al * bf2f(v.w);
  }
  *(float4*)&ctx_p[(size_t)sq * (B_DIM * H_DIM) + b * H_DIM + h] = acc;
}

// ---------------- K5: reduce context partials -> d_out ----------------
__global__ void k_ctx_reduce(const float* __restrict__ ctx_p, float* __restrict__ ctx) {
  const int i = blockIdx.x * 256 + threadIdx.x;
  ctx[i] = ctx_p[i] + ctx_p[32768 + i] + ctx_p[65536 + i] + ctx_p[98304 + i];
}

extern "C" void kernel_launch(void* const* d_in, const int* in_sizes, int n_in,
                              void* d_out, int out_size, void* d_ws, size_t ws_size,
                              hipStream_t stream) {
  (void)in_sizes; (void)n_in; (void)out_size; (void)ws_size;
  const float* dh  = (const float*)d_in[0];
  const float* enc = (const float*)d_in[1];
  const float* Uw  = (const float*)d_in[2];
  const float* Ww  = (const float*)d_in[3];
  const float* vw  = (const float*)d_in[4];
  float* ctx_out = (float*)d_out;                 // [32,1024]
  float* alpha   = (float*)d_out + M_DIM;         // [32,1024]

  char* ws = (char*)d_ws;
  const size_t EB_BYTES = (size_t)M_DIM * H_DIM * 2;            // 64 MiB

  unsigned short* Eb = (unsigned short*)ws;
  unsigned short* Wb = (unsigned short*)(ws + EB_BYTES);
  float* Uh    = (float*)(ws + EB_BYTES + (2u << 20));
  float* att_p = (float*)(ws + EB_BYTES + (2u << 20) + (128u << 10));
  float* ctx_p = (float*)(ws + EB_BYTES + (2u << 20) + (128u << 10) + (1u << 20));

  k_prep_all<<<4096, 256, 0, stream>>>(enc, Eb, Ww, Wb, dh, Uw, Uh);
  k_att7<<<512, 512, 0, stream>>>(Eb, Wb, Uh, vw, att_p);
  k_ctx_sm<<<128, 256, 0, stream>>>(Eb, att_p, alpha, ctx_p);
  k_ctx_reduce<<<128, 256, 0, stream>>>(ctx_p, ctx_out);
}